// Round 6
// baseline (1406.502 us; speedup 1.0000x reference)
//
#include <hip/hip_runtime.h>
#include <math.h>

#define DMODEL 256
#define HEADS 8
#define DHEAD 32
#define LEVELS 4
#define POINTS 4
#define NLAYERS 6
#define DFF 1024
#define BS 4
#define NQ 900
#define SLEN 19560
#define EPS_LN 1e-5f
#define ATT_SCALE 0.17677669529663689f

typedef __attribute__((ext_vector_type(8))) short bf16x8;
typedef __attribute__((ext_vector_type(4))) float f32x4;
typedef __attribute__((ext_vector_type(4))) unsigned short u16x4;
typedef __attribute__((ext_vector_type(8))) unsigned short u16x8;

__device__ __forceinline__ unsigned short f2b(float x) {
  unsigned u = __float_as_uint(x);
  u += 0x7FFF + ((u >> 16) & 1);
  return (unsigned short)(u >> 16);
}
__device__ __forceinline__ float b2f(unsigned short v) {
  return __uint_as_float(((unsigned)v) << 16);
}

// ---------------------------------------------------------------- prologue elementwise
// cur=tgt f32, cur_bf=bf16(tgt), qpos_bf=bf16(qpos)
__global__ __launch_bounds__(256) void copycvt_k(const float* __restrict__ a,
                                                 const float* __restrict__ qp,
                                                 float* __restrict__ cf,
                                                 unsigned short* __restrict__ cb,
                                                 unsigned short* __restrict__ qb, int n4) {
  int i = blockIdx.x * 256 + threadIdx.x;
  if (i < n4) {
    float4 v = reinterpret_cast<const float4*>(a)[i];
    float4 q = reinterpret_cast<const float4*>(qp)[i];
    reinterpret_cast<float4*>(cf)[i] = v;
    u16x4 o4 = {f2b(v.x), f2b(v.y), f2b(v.z), f2b(v.w)};
    reinterpret_cast<u16x4*>(cb)[i] = o4;
    u16x4 p4 = {f2b(q.x), f2b(q.y), f2b(q.z), f2b(q.w)};
    reinterpret_cast<u16x4*>(qb)[i] = p4;
  }
}

// fused bf16 conversion of src + 6 weight tensors
#define N4_SRC (SLEN * BS * DMODEL / 4)
#define N4_SAIN (NLAYERS * 768 * 256 / 4)
#define N4_SQ (NLAYERS * 256 * 256 / 4)
#define N4_FFN (NLAYERS * DFF * 256 / 4)
__global__ __launch_bounds__(256) void f2ball_k(
    const float* __restrict__ s0, const float* __restrict__ s1,
    const float* __restrict__ s2, const float* __restrict__ s3,
    const float* __restrict__ s4, const float* __restrict__ s5,
    const float* __restrict__ s6,
    unsigned short* __restrict__ d0, unsigned short* __restrict__ d1,
    unsigned short* __restrict__ d2, unsigned short* __restrict__ d3,
    unsigned short* __restrict__ d4, unsigned short* __restrict__ d5,
    unsigned short* __restrict__ d6) {
  const int total = N4_SRC + N4_SAIN + 3 * N4_SQ + 2 * N4_FFN;
  for (int i = blockIdx.x * 256 + threadIdx.x; i < total; i += gridDim.x * 256) {
    const float* s;
    unsigned short* d;
    int j = i;
    if (j < N4_SRC) { s = s0; d = d0; }
    else { j -= N4_SRC;
      if (j < N4_SAIN) { s = s1; d = d1; }
      else { j -= N4_SAIN;
        if (j < N4_SQ) { s = s2; d = d2; }
        else { j -= N4_SQ;
          if (j < N4_SQ) { s = s3; d = d3; }
          else { j -= N4_SQ;
            if (j < N4_SQ) { s = s4; d = d4; }
            else { j -= N4_SQ;
              if (j < N4_FFN) { s = s5; d = d5; }
              else { j -= N4_FFN; s = s6; d = d6; } } } } } }
    float4 v = reinterpret_cast<const float4*>(s)[j];
    u16x4 o4 = {f2b(v.x), f2b(v.y), f2b(v.z), f2b(v.w)};
    reinterpret_cast<u16x4*>(d)[j] = o4;
  }
}

// concat samp_w(256x256)+attn_w(128x256) -> [NLAYERS][384][256] bf16, biases -> f32
__global__ __launch_bounds__(256) void catw_k(const float* __restrict__ sw,
                                              const float* __restrict__ aw,
                                              const float* __restrict__ sb,
                                              const float* __restrict__ ab,
                                              unsigned short* __restrict__ wout,
                                              float* __restrict__ bout) {
  int i = blockIdx.x * 256 + threadIdx.x;
  const int total4 = NLAYERS * 384 * 256 / 4;
  if (i < total4) {
    int l = i / (384 * 64);
    int r = i % (384 * 64);
    int row = r / 64;
    int c4 = r % 64;
    const float* srcp = row < 256
        ? sw + ((size_t)l * 256 * 256 + (size_t)row * 256 + c4 * 4)
        : aw + ((size_t)l * 128 * 256 + (size_t)(row - 256) * 256 + c4 * 4);
    float4 v = *(const float4*)srcp;
    u16x4 o4 = {f2b(v.x), f2b(v.y), f2b(v.z), f2b(v.w)};
    *(u16x4*)(wout + (size_t)i * 4) = o4;
  }
  if (i < NLAYERS * 384) {
    int l = i / 384, r = i % 384;
    bout[i] = r < 256 ? sb[l * 256 + r] : ab[l * 128 + (r - 256)];
  }
}

// stack q,k rows (first 512 of each layer's in_w) -> qkW [6*512][256] bf16, bqk f32
__global__ __launch_bounds__(256) void stackqk_k(const float* __restrict__ w_in,
                                                 const float* __restrict__ b_in,
                                                 unsigned short* __restrict__ qkW,
                                                 float* __restrict__ bqk) {
  int i = blockIdx.x * 256 + threadIdx.x;
  const int total4 = NLAYERS * 512 * 256 / 4;
  if (i < total4) {
    int l = i / (512 * 64);
    int r = i % (512 * 64);
    int row = r / 64, c4 = r % 64;
    float4 v = *(const float4*)(w_in + (size_t)l * 768 * 256 + (size_t)row * 256 + c4 * 4);
    u16x4 o4 = {f2b(v.x), f2b(v.y), f2b(v.z), f2b(v.w)};
    *(u16x4*)(qkW + ((size_t)(l * 512 + row) * 256 + c4 * 4)) = o4;
  }
  if (i < NLAYERS * 512) {
    int l = i / 512, r = i % 512;
    bqk[i] = b_in[l * 768 + r];
  }
}

// ---------------------------------------------------------------- bf16 MFMA GEMM, 64x64 tile
// out[M,N](ld=ldo) = A[M,K] @ W[N,K]^T; per-col: col<res_n -> + res[row*ldr+col]
// (res includes bias), else + bias[col]. Optional relu; f32 and/or bf16 out.
__global__ __launch_bounds__(256) void gemm_bf_k(const unsigned short* __restrict__ A,
                                                 const unsigned short* __restrict__ W,
                                                 const float* __restrict__ bias,
                                                 const float* __restrict__ res,
                                                 int res_n, int ldr,
                                                 float* __restrict__ outf,
                                                 unsigned short* __restrict__ outb,
                                                 int ldo, int M, int N, int K, int relu) {
  __shared__ unsigned short As[64][72];
  __shared__ unsigned short Ws[64][72];
  const int tid = threadIdx.x;
  const int lane = tid & 63, wv = tid >> 6;
  const int wm = wv >> 1, wn = wv & 1;
  const int m0 = blockIdx.x * 64, n0 = blockIdx.y * 64;
  const int l15 = lane & 15, l4 = lane >> 4;

  f32x4 acc[2][2] = {};
  for (int k0 = 0; k0 < K; k0 += 64) {
#pragma unroll
    for (int t = 0; t < 2; ++t) {
      int u = t * 256 + tid;
      int r = u >> 3, c8 = u & 7;
      int ra = m0 + r; if (ra >= M) ra = M - 1;
      *(u16x8*)&As[r][c8 * 8] = *(const u16x8*)(A + (size_t)ra * K + k0 + c8 * 8);
      *(u16x8*)&Ws[r][c8 * 8] = *(const u16x8*)(W + (size_t)(n0 + r) * K + k0 + c8 * 8);
    }
    __syncthreads();
#pragma unroll
    for (int ks = 0; ks < 64; ks += 32) {
      bf16x8 af[2], wf[2];
#pragma unroll
      for (int fr = 0; fr < 2; ++fr)
        af[fr] = *(const bf16x8*)&As[wm * 32 + fr * 16 + l15][ks + l4 * 8];
#pragma unroll
      for (int fn = 0; fn < 2; ++fn)
        wf[fn] = *(const bf16x8*)&Ws[wn * 32 + fn * 16 + l15][ks + l4 * 8];
#pragma unroll
      for (int fr = 0; fr < 2; ++fr)
#pragma unroll
        for (int fn = 0; fn < 2; ++fn)
          acc[fr][fn] = __builtin_amdgcn_mfma_f32_16x16x32_bf16(
              af[fr], wf[fn], acc[fr][fn], 0, 0, 0);
    }
    __syncthreads();
  }
#pragma unroll
  for (int fr = 0; fr < 2; ++fr)
#pragma unroll
    for (int fn = 0; fn < 2; ++fn) {
      int col = n0 + wn * 32 + fn * 16 + l15;
      float bs = bias[col];
#pragma unroll
      for (int j = 0; j < 4; ++j) {
        int row = m0 + wm * 32 + fr * 16 + l4 * 4 + j;
        if (row >= M) continue;
        float v = acc[fr][fn][j];
        if (res && col < res_n) v += res[(size_t)row * ldr + col];
        else v += bs;
        if (relu) v = fmaxf(v, 0.f);
        if (outf) outf[(size_t)row * ldo + col] = v;
        if (outb) outb[(size_t)row * ldo + col] = f2b(v);
      }
    }
}

// ---------------------------------------------------------------- fused GEMM(N=256) + residual + LayerNorm
// y = LN(res + A@W^T + bias); outf f32 (may alias res), outb bf16 optional.
__global__ __launch_bounds__(256) void gemm_lnres_k(const unsigned short* __restrict__ A,
                                                    const unsigned short* __restrict__ W,
                                                    const float* __restrict__ bias,
                                                    const float* __restrict__ res,
                                                    const float* __restrict__ lnw,
                                                    const float* __restrict__ lnb,
                                                    float* __restrict__ outf,
                                                    unsigned short* __restrict__ outb,
                                                    int M, int K) {
  __shared__ unsigned short As[32][72];
  __shared__ unsigned short Ws[256][72];
  __shared__ float Os[32][264];
  const int tid = threadIdx.x;
  const int lane = tid & 63, wv = tid >> 6;
  const int l15 = lane & 15, l4 = lane >> 4;
  const int m0 = blockIdx.x * 32;

  f32x4 acc[2][4] = {};
  for (int k0 = 0; k0 < K; k0 += 64) {
    {
      int r = tid >> 3, c8 = tid & 7;
      int ra = m0 + r; if (ra >= M) ra = M - 1;
      *(u16x8*)&As[r][c8 * 8] = *(const u16x8*)(A + (size_t)ra * K + k0 + c8 * 8);
#pragma unroll
      for (int t = 0; t < 8; ++t) {
        int u = t * 256 + tid;
        int wr = u >> 3, wc = u & 7;
        *(u16x8*)&Ws[wr][wc * 8] = *(const u16x8*)(W + (size_t)wr * K + k0 + wc * 8);
      }
    }
    __syncthreads();
#pragma unroll
    for (int ks = 0; ks < 64; ks += 32) {
      bf16x8 af[2], wf[4];
#pragma unroll
      for (int fr = 0; fr < 2; ++fr)
        af[fr] = *(const bf16x8*)&As[fr * 16 + l15][ks + l4 * 8];
#pragma unroll
      for (int fc = 0; fc < 4; ++fc)
        wf[fc] = *(const bf16x8*)&Ws[wv * 64 + fc * 16 + l15][ks + l4 * 8];
#pragma unroll
      for (int fr = 0; fr < 2; ++fr)
#pragma unroll
        for (int fc = 0; fc < 4; ++fc)
          acc[fr][fc] = __builtin_amdgcn_mfma_f32_16x16x32_bf16(
              af[fr], wf[fc], acc[fr][fc], 0, 0, 0);
    }
    __syncthreads();
  }
  // epilogue: bias + residual -> LDS
#pragma unroll
  for (int fr = 0; fr < 2; ++fr)
#pragma unroll
    for (int fc = 0; fc < 4; ++fc) {
      int col = wv * 64 + fc * 16 + l15;
      float bs = bias[col];
#pragma unroll
      for (int j = 0; j < 4; ++j) {
        int row = fr * 16 + l4 * 4 + j;
        int grow = m0 + row;
        float v = acc[fr][fc][j] + bs + (grow < M ? res[(size_t)grow * 256 + col] : 0.f);
        Os[row][col] = v;
      }
    }
  __syncthreads();
  // LayerNorm: wave wv handles rows wv*8 .. wv*8+7
  float4 wv4 = *(const float4*)(lnw + lane * 4);
  float4 bv4 = *(const float4*)(lnb + lane * 4);
#pragma unroll
  for (int i = 0; i < 8; ++i) {
    int row = wv * 8 + i;
    int grow = m0 + row;
    float4 x = *(float4*)&Os[row][lane * 4];
    float s = x.x + x.y + x.z + x.w;
#pragma unroll
    for (int m = 1; m < 64; m <<= 1) s += __shfl_xor(s, m);
    const float mu = s * (1.f / DMODEL);
    float4 v = {x.x - mu, x.y - mu, x.z - mu, x.w - mu};
    float q = v.x * v.x + v.y * v.y + v.z * v.z + v.w * v.w;
#pragma unroll
    for (int m = 1; m < 64; m <<= 1) q += __shfl_xor(q, m);
    const float rstd = rsqrtf(q * (1.f / DMODEL) + EPS_LN);
    float4 y = {v.x * rstd * wv4.x + bv4.x, v.y * rstd * wv4.y + bv4.y,
                v.z * rstd * wv4.z + bv4.z, v.w * rstd * wv4.w + bv4.w};
    if (grow < M) {
      *(float4*)(outf + (size_t)grow * 256 + lane * 4) = y;
      if (outb) {
        u16x4 ob = {f2b(y.x), f2b(y.y), f2b(y.z), f2b(y.w)};
        *(u16x4*)(outb + (size_t)grow * 256 + lane * 4) = ob;
      }
    }
  }
}

// ---------------------------------------------------------------- bf16 MFMA GEMM (value proj, 128x128)
__global__ __launch_bounds__(256) void gemm_vmfma_k(const unsigned short* __restrict__ A,
                                                    const unsigned short* __restrict__ W,
                                                    const float* __restrict__ bias,
                                                    unsigned short* __restrict__ C,
                                                    int M) {
  __shared__ unsigned short As[128][72];
  __shared__ unsigned short Ws[128][72];
  const int tid = threadIdx.x;
  const int lane = tid & 63, wv = tid >> 6;
  const int wm = wv >> 1, wn = wv & 1;
  const int m0 = blockIdx.x * 128, n0 = blockIdx.y * 128;
  const int l15 = lane & 15, l4 = lane >> 4;

  f32x4 acc[4][4] = {};

  for (int k0 = 0; k0 < 256; k0 += 64) {
#pragma unroll
    for (int t = 0; t < 4; ++t) {
      int u = t * 256 + tid;
      int r = u >> 3, c8 = u & 7;
      int ra = m0 + r; if (ra >= M) ra = M - 1;
      *(u16x8*)&As[r][c8 * 8] = *(const u16x8*)(A + (size_t)ra * 256 + k0 + c8 * 8);
      *(u16x8*)&Ws[r][c8 * 8] = *(const u16x8*)(W + (size_t)(n0 + r) * 256 + k0 + c8 * 8);
    }
    __syncthreads();
#pragma unroll
    for (int ks = 0; ks < 64; ks += 32) {
      bf16x8 af[4], bf[4];
#pragma unroll
      for (int fr = 0; fr < 4; ++fr)
        af[fr] = *(const bf16x8*)&As[wm * 64 + fr * 16 + l15][ks + l4 * 8];
#pragma unroll
      for (int fn = 0; fn < 4; ++fn)
        bf[fn] = *(const bf16x8*)&Ws[wn * 64 + fn * 16 + l15][ks + l4 * 8];
#pragma unroll
      for (int fr = 0; fr < 4; ++fr)
#pragma unroll
        for (int fn = 0; fn < 4; ++fn)
          acc[fr][fn] = __builtin_amdgcn_mfma_f32_16x16x32_bf16(
              af[fr], bf[fn], acc[fr][fn], 0, 0, 0);
    }
    __syncthreads();
  }
#pragma unroll
  for (int fr = 0; fr < 4; ++fr)
#pragma unroll
    for (int fn = 0; fn < 4; ++fn) {
      int col = n0 + wn * 64 + fn * 16 + l15;
      float bs = bias[col];
#pragma unroll
      for (int j = 0; j < 4; ++j) {
        int row = m0 + wm * 64 + fr * 16 + l4 * 4 + j;
        if (row < M) C[(size_t)row * 256 + col] = f2b(acc[fr][fn][j] + bs);
      }
    }
}

// ---------------------------------------------------------------- MFMA flash self-attn
__global__ __launch_bounds__(256) void fattn_mfma_k(const unsigned short* __restrict__ qkv,
                                                    unsigned short* __restrict__ o) {
  __shared__ unsigned short Qlds[64][40];
  __shared__ unsigned short Klds[64][40];
  __shared__ unsigned short Vt[32][72];   // V transposed [dh][key]
  __shared__ unsigned short Plds[64][72];
  const int tid = threadIdx.x;
  const int lane = tid & 63;
  const int wq = tid >> 6;
  const int l15 = lane & 15, l4 = lane >> 4;
  const int q0 = blockIdx.x * 64;
  const int h = blockIdx.y, b = blockIdx.z;
  const int hq = h * 32;
  const size_t rowb = (size_t)b * NQ;

  {
    int q = q0 + (tid >> 2);
    int qc = q < NQ ? q : NQ - 1;
    *(u16x8*)&Qlds[tid >> 2][(tid & 3) * 8] =
        *(const u16x8*)(qkv + (rowb + qc) * 768 + hq + (tid & 3) * 8);
  }
  __syncthreads();
  const bf16x8 qf = *(const bf16x8*)&Qlds[wq * 16 + l15][l4 * 8];

  float m_r[4] = {-1e30f, -1e30f, -1e30f, -1e30f};
  float l_r[4] = {0.f, 0.f, 0.f, 0.f};
  f32x4 oacc[2] = {};

  for (int k0 = 0; k0 < NQ; k0 += 64) {
    __syncthreads();
    {
      int kk = k0 + (tid >> 2);
      int kc = kk < NQ ? kk : NQ - 1;
      const unsigned short* kbase = qkv + (rowb + kc) * 768 + hq + (tid & 3) * 8;
      u16x8 kv = *(const u16x8*)(kbase + 256);
      u16x8 vv = *(const u16x8*)(kbase + 512);
      *(u16x8*)&Klds[tid >> 2][(tid & 3) * 8] = kv;
#pragma unroll
      for (int i = 0; i < 8; ++i) Vt[(tid & 3) * 8 + i][tid >> 2] = vv[i];
    }
    __syncthreads();

    f32x4 s[4];
#pragma unroll
    for (int fc = 0; fc < 4; ++fc) {
      bf16x8 kf = *(const bf16x8*)&Klds[fc * 16 + l15][l4 * 8];
      s[fc] = __builtin_amdgcn_mfma_f32_16x16x32_bf16(qf, kf, (f32x4){0.f, 0.f, 0.f, 0.f}, 0, 0, 0);
    }
#pragma unroll
    for (int fc = 0; fc < 4; ++fc) {
      bool oob = (k0 + fc * 16 + l15) >= NQ;
#pragma unroll
      for (int j = 0; j < 4; ++j)
        s[fc][j] = oob ? -1e30f : s[fc][j] * ATT_SCALE;
    }
#pragma unroll
    for (int j = 0; j < 4; ++j) {
      float tm = fmaxf(fmaxf(s[0][j], s[1][j]), fmaxf(s[2][j], s[3][j]));
      tm = fmaxf(tm, __shfl_xor(tm, 1, 16));
      tm = fmaxf(tm, __shfl_xor(tm, 2, 16));
      tm = fmaxf(tm, __shfl_xor(tm, 4, 16));
      tm = fmaxf(tm, __shfl_xor(tm, 8, 16));
      float mn = fmaxf(m_r[j], tm);
      float sf = __expf(m_r[j] - mn);
      m_r[j] = mn;
      oacc[0][j] *= sf;
      oacc[1][j] *= sf;
      float rs = 0.f;
#pragma unroll
      for (int fc = 0; fc < 4; ++fc) {
        float pv = __expf(s[fc][j] - mn);
        s[fc][j] = pv;
        rs += pv;
      }
      rs += __shfl_xor(rs, 1, 16);
      rs += __shfl_xor(rs, 2, 16);
      rs += __shfl_xor(rs, 4, 16);
      rs += __shfl_xor(rs, 8, 16);
      l_r[j] = l_r[j] * sf + rs;
    }
#pragma unroll
    for (int fc = 0; fc < 4; ++fc)
#pragma unroll
      for (int j = 0; j < 4; ++j)
        Plds[wq * 16 + l4 * 4 + j][fc * 16 + l15] = f2b(s[fc][j]);
    __syncthreads();
#pragma unroll
    for (int ks = 0; ks < 2; ++ks) {
      bf16x8 pf = *(const bf16x8*)&Plds[wq * 16 + l15][ks * 32 + l4 * 8];
#pragma unroll
      for (int oc = 0; oc < 2; ++oc) {
        bf16x8 vf = *(const bf16x8*)&Vt[oc * 16 + l15][ks * 32 + l4 * 8];
        oacc[oc] = __builtin_amdgcn_mfma_f32_16x16x32_bf16(pf, vf, oacc[oc], 0, 0, 0);
      }
    }
  }
#pragma unroll
  for (int j = 0; j < 4; ++j) {
    int q = q0 + wq * 16 + l4 * 4 + j;
    if (q < NQ) {
      float inv = 1.f / l_r[j];
      o[(rowb + q) * 256 + hq + l15] = f2b(oacc[0][j] * inv);
      o[(rowb + q) * 256 + hq + 16 + l15] = f2b(oacc[1][j] * inv);
    }
  }
}

// ---------------------------------------------------------------- MSDA sample
__global__ __launch_bounds__(256) void msda_k(const float* __restrict__ refp,
                                              const float* __restrict__ vr,
                                              const unsigned short* __restrict__ value,
                                              const float* __restrict__ cat,
                                              unsigned short* __restrict__ outp) {
  const int HW[4][2] = {{92, 160}, {46, 80}, {23, 40}, {12, 20}};
  const int START[4] = {0, 14720, 18400, 19320};
  const int qi = blockIdx.x, b = blockIdx.y;
  const int tid = threadIdx.x;
  const int h = tid >> 5;
  const int r = tid & 31;
  const int lvl = r >> 3;
  const int li = r & 7;
  const size_t base = (size_t)(b * NQ + qi);
  const float rx = refp[base * 3 + 0];
  const float rz = refp[base * 3 + 2];

  const float* lg = cat + base * 384 + 256 + h * 16;
  float4 L0 = *(const float4*)(lg + 0);
  float4 L1 = *(const float4*)(lg + 4);
  float4 L2 = *(const float4*)(lg + 8);
  float4 L3 = *(const float4*)(lg + 12);
  float mx = fmaxf(fmaxf(fmaxf(L0.x, L0.y), fmaxf(L0.z, L0.w)),
                   fmaxf(fmaxf(fmaxf(L1.x, L1.y), fmaxf(L1.z, L1.w)),
                         fmaxf(fmaxf(fmaxf(L2.x, L2.y), fmaxf(L2.z, L2.w)),
                               fmaxf(fmaxf(L3.x, L3.y), fmaxf(L3.z, L3.w)))));
  float4 E0 = {__expf(L0.x - mx), __expf(L0.y - mx), __expf(L0.z - mx), __expf(L0.w - mx)};
  float4 E1 = {__expf(L1.x - mx), __expf(L1.y - mx), __expf(L1.z - mx), __expf(L1.w - mx)};
  float4 E2 = {__expf(L2.x - mx), __expf(L2.y - mx), __expf(L2.z - mx), __expf(L2.w - mx)};
  float4 E3 = {__expf(L3.x - mx), __expf(L3.y - mx), __expf(L3.z - mx), __expf(L3.w - mx)};
  float sum = E0.x + E0.y + E0.z + E0.w + E1.x + E1.y + E1.z + E1.w +
              E2.x + E2.y + E2.z + E2.w + E3.x + E3.y + E3.z + E3.w;
  const float inv = 1.f / sum;
  float4 Emy = lvl == 0 ? E0 : lvl == 1 ? E1 : lvl == 2 ? E2 : E3;
  float wl[4] = {Emy.x * inv, Emy.y * inv, Emy.z * inv, Emy.w * inv};

  const int H = HW[lvl][0], W = HW[lvl][1];
  const float refx = rx * vr[(b * LEVELS + lvl) * 2 + 0] * (float)W;
  const float refy = rz * vr[(b * LEVELS + lvl) * 2 + 1] * (float)H;
  const unsigned short* vbase = value + ((size_t)b * SLEN + START[lvl]) * DMODEL + h * DHEAD + li * 4;
  const float* ob = cat + base * 384 + h * 32 + lvl * 8;

  float a0 = 0.f, a1 = 0.f, a2 = 0.f, a3 = 0.f;
#pragma unroll
  for (int p = 0; p < 4; ++p) {
    const float x = refx + ob[p * 2 + 0] - 0.5f;
    const float y = refy + ob[p * 2 + 1] - 0.5f;
    const float x0f = floorf(x), y0f = floorf(y);
    const float fx = x - x0f, fy = y - y0f;
    const int x0 = (int)x0f, y0 = (int)y0f;
#pragma unroll
    for (int ci = 0; ci < 4; ++ci) {
      const int xi = x0 + (ci & 1);
      const int yi = y0 + (ci >> 1);
      if ((xi >= 0) && (xi < W) && (yi >= 0) && (yi < H)) {
        const float wxy = ((ci & 1) ? fx : 1.f - fx) * ((ci >> 1) ? fy : 1.f - fy) * wl[p];
        u16x4 v4 = *(const u16x4*)(vbase + (size_t)(yi * W + xi) * DMODEL);
        a0 = fmaf(wxy, b2f(v4[0]), a0);
        a1 = fmaf(wxy, b2f(v4[1]), a1);
        a2 = fmaf(wxy, b2f(v4[2]), a2);
        a3 = fmaf(wxy, b2f(v4[3]), a3);
      }
    }
  }
  a0 += __shfl_xor(a0, 8);  a1 += __shfl_xor(a1, 8);
  a2 += __shfl_xor(a2, 8);  a3 += __shfl_xor(a3, 8);
  a0 += __shfl_xor(a0, 16); a1 += __shfl_xor(a1, 16);
  a2 += __shfl_xor(a2, 16); a3 += __shfl_xor(a3, 16);
  if (lvl == 0) {
    u16x4 o4 = {f2b(a0), f2b(a1), f2b(a2), f2b(a3)};
    *(u16x4*)(outp + base * 256 + h * 32 + li * 4) = o4;
  }
}

// ---------------------------------------------------------------- launcher
extern "C" void kernel_launch(void* const* d_in, const int* in_sizes, int n_in,
                              void* d_out, int out_size, void* d_ws, size_t ws_size,
                              hipStream_t stream) {
  const float* tgt     = (const float*)d_in[0];
  const float* refp    = (const float*)d_in[1];
  const float* src     = (const float*)d_in[2];
  const float* vr      = (const float*)d_in[3];
  const float* qpos    = (const float*)d_in[4];
  const float* sa_in_w = (const float*)d_in[5];
  const float* sa_in_b = (const float*)d_in[6];
  const float* sa_out_w= (const float*)d_in[7];
  const float* sa_out_b= (const float*)d_in[8];
  const float* samp_w  = (const float*)d_in[9];
  const float* samp_b  = (const float*)d_in[10];
  const float* attn_w  = (const float*)d_in[11];
  const float* attn_b  = (const float*)d_in[12];
  const float* val_w   = (const float*)d_in[13];
  const float* val_b   = (const float*)d_in[14];
  const float* ca_out_w= (const float*)d_in[15];
  const float* ca_out_b= (const float*)d_in[16];
  const float* ffn1_w  = (const float*)d_in[17];
  const float* ffn1_b  = (const float*)d_in[18];
  const float* ffn2_w  = (const float*)d_in[19];
  const float* ffn2_b  = (const float*)d_in[20];
  const float* ln1_w   = (const float*)d_in[21];
  const float* ln1_b   = (const float*)d_in[22];
  const float* ln2_w   = (const float*)d_in[23];
  const float* ln2_b   = (const float*)d_in[24];
  const float* ln3_w   = (const float*)d_in[25];
  const float* ln3_b   = (const float*)d_in[26];

  const int M = BS * NQ;                 // 3600
  const int MV = BS * SLEN;              // 78240
  const size_t TOK = (size_t)M * DMODEL; // 921600

  float* ws = (float*)d_ws;
  size_t off = 0;
  auto alloc = [&](size_t n) { float* p = ws + off; off += n; return p; };
  auto allocb = [&](size_t n) { unsigned short* p = (unsigned short*)(ws + off); off += (n + 1) / 2; return p; };
  float* cur     = alloc(TOK);
  float* catout  = alloc((size_t)M * 384);
  float* b_cacat = alloc((size_t)NLAYERS * 384);
  float* bqk     = alloc((size_t)NLAYERS * 512);
  float* qpos_qk = alloc((size_t)M * NLAYERS * 512);   // [M][3072]
  float* qpos_cat= alloc((size_t)M * NLAYERS * 384);   // [M][2304]
  unsigned short* cur_bf  = allocb(TOK);
  unsigned short* qpos_bf = allocb(TOK);
  unsigned short* sao_bf  = allocb(TOK);
  unsigned short* msda_bf = allocb(TOK);
  unsigned short* qkv_bf  = allocb((size_t)M * 768);
  unsigned short* ffnh_bf = allocb((size_t)M * DFF);
  unsigned short* src_bf  = allocb((size_t)MV * DMODEL);
  unsigned short* value_bf= allocb((size_t)MV * DMODEL);
  unsigned short* w_in_bf   = allocb((size_t)NLAYERS * 768 * 256);
  unsigned short* w_saout_bf= allocb((size_t)NLAYERS * 256 * 256);
  unsigned short* w_cacat_bf= allocb((size_t)NLAYERS * 384 * 256);
  unsigned short* w_val_bf  = allocb((size_t)NLAYERS * 256 * 256);
  unsigned short* w_caout_bf= allocb((size_t)NLAYERS * 256 * 256);
  unsigned short* w_ffn1_bf = allocb((size_t)NLAYERS * DFF * 256);
  unsigned short* w_ffn2_bf = allocb((size_t)NLAYERS * 256 * DFF);
  unsigned short* qkW_bf    = allocb((size_t)NLAYERS * 512 * 256);

  const int n4 = (int)(TOK / 4);
  const dim3 blk(256);
  const dim3 gE((n4 + 255) / 256);

  // prologue
  copycvt_k<<<gE, blk, 0, stream>>>(tgt, qpos, cur, cur_bf, qpos_bf, n4);
  f2ball_k<<<dim3(2048), blk, 0, stream>>>(src, sa_in_w, sa_out_w, val_w, ca_out_w,
                                           ffn1_w, ffn2_w,
                                           src_bf, w_in_bf, w_saout_bf, w_val_bf,
                                           w_caout_bf, w_ffn1_bf, w_ffn2_bf);
  catw_k<<<dim3(576), blk, 0, stream>>>(samp_w, attn_w, samp_b, attn_b, w_cacat_bf, b_cacat);
  stackqk_k<<<dim3(768), blk, 0, stream>>>(sa_in_w, sa_in_b, qkW_bf, bqk);
  // qpos projections (include biases)
  gemm_bf_k<<<dim3(57, 48), blk, 0, stream>>>(qpos_bf, qkW_bf, bqk, nullptr, 0, 0,
                                              qpos_qk, nullptr, 3072, M, 3072, 256, 0);
  gemm_bf_k<<<dim3(57, 36), blk, 0, stream>>>(qpos_bf, w_cacat_bf, b_cacat, nullptr, 0, 0,
                                              qpos_cat, nullptr, 2304, M, 2304, 256, 0);

  const dim3 gQKV(57, 12);   // N=768
  const dim3 gCat(57, 6);    // N=384
  const dim3 gF1(57, 16);    // N=1024
  const dim3 gLN(113);       // fused gemm+LN, 32-row tiles

  for (int l = 0; l < NLAYERS; ++l) {
    // QKV: q,k cols get precomputed (qpos@W + b); v cols get bias
    gemm_bf_k<<<gQKV, blk, 0, stream>>>(cur_bf, w_in_bf + (size_t)l * 768 * 256,
                                        sa_in_b + l * 768,
                                        qpos_qk + (size_t)l * 512, 512, 3072,
                                        nullptr, qkv_bf, 768, M, 768, 256, 0);

    fattn_mfma_k<<<dim3((NQ + 63) / 64, HEADS, BS), blk, 0, stream>>>(qkv_bf, sao_bf);

    gemm_lnres_k<<<gLN, blk, 0, stream>>>(sao_bf, w_saout_bf + (size_t)l * 256 * 256,
                                          sa_out_b + l * 256, cur,
                                          ln1_w + l * 256, ln1_b + l * 256,
                                          cur, cur_bf, M, 256);

    // cross-attn (MSDA)
    gemm_vmfma_k<<<dim3((MV + 127) / 128, 2), blk, 0, stream>>>(
        src_bf, w_val_bf + (size_t)l * 256 * 256, val_b + l * 256, value_bf, MV);
    gemm_bf_k<<<gCat, blk, 0, stream>>>(cur_bf, w_cacat_bf + (size_t)l * 384 * 256,
                                        b_cacat + l * 384,
                                        qpos_cat + (size_t)l * 384, 384, 2304,
                                        catout, nullptr, 384, M, 384, 256, 0);

    msda_k<<<dim3(NQ, BS), blk, 0, stream>>>(refp, vr, value_bf, catout, msda_bf);

    gemm_lnres_k<<<gLN, blk, 0, stream>>>(msda_bf, w_caout_bf + (size_t)l * 256 * 256,
                                          ca_out_b + l * 256, cur,
                                          ln2_w + l * 256, ln2_b + l * 256,
                                          cur, cur_bf, M, 256);

    // FFN
    gemm_bf_k<<<gF1, blk, 0, stream>>>(cur_bf, w_ffn1_bf + (size_t)l * DFF * 256,
                                       ffn1_b + l * DFF, nullptr, 0, 0,
                                       nullptr, ffnh_bf, DFF, M, DFF, 256, 1);
    const bool last = (l == NLAYERS - 1);
    gemm_lnres_k<<<gLN, blk, 0, stream>>>(ffnh_bf, w_ffn2_bf + (size_t)l * 256 * DFF,
                                          ffn2_b + l * 256, cur,
                                          ln3_w + l * 256, ln3_b + l * 256,
                                          last ? (float*)d_out : cur,
                                          last ? nullptr : cur_bf, M, DFF);
  }
}

// Round 7
// 1226.027 us; speedup vs baseline: 1.1472x; 1.1472x over previous
//
#include <hip/hip_runtime.h>
#include <math.h>

#define DMODEL 256
#define HEADS 8
#define DHEAD 32
#define LEVELS 4
#define POINTS 4
#define NLAYERS 6
#define DFF 1024
#define BS 4
#define NQ 900
#define SLEN 19560
#define EPS_LN 1e-5f
#define ATT_SCALE 0.17677669529663689f

typedef __attribute__((ext_vector_type(8))) short bf16x8;
typedef __attribute__((ext_vector_type(4))) float f32x4;
typedef __attribute__((ext_vector_type(4))) unsigned short u16x4;
typedef __attribute__((ext_vector_type(8))) unsigned short u16x8;

__device__ __forceinline__ unsigned short f2b(float x) {
  unsigned u = __float_as_uint(x);
  u += 0x7FFF + ((u >> 16) & 1);
  return (unsigned short)(u >> 16);
}
__device__ __forceinline__ float b2f(unsigned short v) {
  return __uint_as_float(((unsigned)v) << 16);
}

// ---------------------------------------------------------------- prologue elementwise
// cur=tgt f32, cur_bf=bf16(tgt), qbuf=bf16(tgt+qpos)
__global__ __launch_bounds__(256) void copycvt_k(const float* __restrict__ a,
                                                 const float* __restrict__ qp,
                                                 float* __restrict__ cf,
                                                 unsigned short* __restrict__ cb,
                                                 unsigned short* __restrict__ qb, int n4) {
  int i = blockIdx.x * 256 + threadIdx.x;
  if (i < n4) {
    float4 v = reinterpret_cast<const float4*>(a)[i];
    float4 q = reinterpret_cast<const float4*>(qp)[i];
    reinterpret_cast<float4*>(cf)[i] = v;
    u16x4 o4 = {f2b(v.x), f2b(v.y), f2b(v.z), f2b(v.w)};
    reinterpret_cast<u16x4*>(cb)[i] = o4;
    u16x4 p4 = {f2b(v.x + q.x), f2b(v.y + q.y), f2b(v.z + q.z), f2b(v.w + q.w)};
    reinterpret_cast<u16x4*>(qb)[i] = p4;
  }
}

// fused bf16 conversion of src + 6 weight tensors
#define N4_SRC (SLEN * BS * DMODEL / 4)
#define N4_SAIN (NLAYERS * 768 * 256 / 4)
#define N4_SQ (NLAYERS * 256 * 256 / 4)
#define N4_FFN (NLAYERS * DFF * 256 / 4)
__global__ __launch_bounds__(256) void f2ball_k(
    const float* __restrict__ s0, const float* __restrict__ s1,
    const float* __restrict__ s2, const float* __restrict__ s3,
    const float* __restrict__ s4, const float* __restrict__ s5,
    const float* __restrict__ s6,
    unsigned short* __restrict__ d0, unsigned short* __restrict__ d1,
    unsigned short* __restrict__ d2, unsigned short* __restrict__ d3,
    unsigned short* __restrict__ d4, unsigned short* __restrict__ d5,
    unsigned short* __restrict__ d6) {
  const int total = N4_SRC + N4_SAIN + 3 * N4_SQ + 2 * N4_FFN;
  for (int i = blockIdx.x * 256 + threadIdx.x; i < total; i += gridDim.x * 256) {
    const float* s;
    unsigned short* d;
    int j = i;
    if (j < N4_SRC) { s = s0; d = d0; }
    else { j -= N4_SRC;
      if (j < N4_SAIN) { s = s1; d = d1; }
      else { j -= N4_SAIN;
        if (j < N4_SQ) { s = s2; d = d2; }
        else { j -= N4_SQ;
          if (j < N4_SQ) { s = s3; d = d3; }
          else { j -= N4_SQ;
            if (j < N4_SQ) { s = s4; d = d4; }
            else { j -= N4_SQ;
              if (j < N4_FFN) { s = s5; d = d5; }
              else { j -= N4_FFN; s = s6; d = d6; } } } } } }
    float4 v = reinterpret_cast<const float4*>(s)[j];
    u16x4 o4 = {f2b(v.x), f2b(v.y), f2b(v.z), f2b(v.w)};
    reinterpret_cast<u16x4*>(d)[j] = o4;
  }
}

// concat samp_w(256x256)+attn_w(128x256) -> [NLAYERS][384][256] bf16, biases -> f32
__global__ __launch_bounds__(256) void catw_k(const float* __restrict__ sw,
                                              const float* __restrict__ aw,
                                              const float* __restrict__ sb,
                                              const float* __restrict__ ab,
                                              unsigned short* __restrict__ wout,
                                              float* __restrict__ bout) {
  int i = blockIdx.x * 256 + threadIdx.x;
  const int total4 = NLAYERS * 384 * 256 / 4;
  if (i < total4) {
    int l = i / (384 * 64);
    int r = i % (384 * 64);
    int row = r / 64;
    int c4 = r % 64;
    const float* srcp = row < 256
        ? sw + ((size_t)l * 256 * 256 + (size_t)row * 256 + c4 * 4)
        : aw + ((size_t)l * 128 * 256 + (size_t)(row - 256) * 256 + c4 * 4);
    float4 v = *(const float4*)srcp;
    u16x4 o4 = {f2b(v.x), f2b(v.y), f2b(v.z), f2b(v.w)};
    *(u16x4*)(wout + (size_t)i * 4) = o4;
  }
  if (i < NLAYERS * 384) {
    int l = i / 384, r = i % 384;
    bout[i] = r < 256 ? sb[l * 256 + r] : ab[l * 128 + (r - 256)];
  }
}

// ---------------------------------------------------------------- bf16 MFMA GEMM, 64x64 tile
// out[M,N](ld=ldo) = Ause[M,K] @ W[N,K]^T + bias; Ause = (n0>=nsplit) ? A2 : A.
// Optional relu; f32 and/or bf16 out.
__global__ __launch_bounds__(256) void gemm_bf_k(const unsigned short* __restrict__ A,
                                                 const unsigned short* __restrict__ A2,
                                                 int nsplit,
                                                 const unsigned short* __restrict__ W,
                                                 const float* __restrict__ bias,
                                                 float* __restrict__ outf,
                                                 unsigned short* __restrict__ outb,
                                                 int ldo, int M, int N, int K, int relu) {
  __shared__ unsigned short As[64][72];
  __shared__ unsigned short Ws[64][72];
  const int tid = threadIdx.x;
  const int lane = tid & 63, wv = tid >> 6;
  const int wm = wv >> 1, wn = wv & 1;
  const int m0 = blockIdx.x * 64, n0 = blockIdx.y * 64;
  const int l15 = lane & 15, l4 = lane >> 4;
  const unsigned short* __restrict__ Ause = (n0 >= nsplit) ? A2 : A;

  f32x4 acc[2][2] = {};
  for (int k0 = 0; k0 < K; k0 += 64) {
#pragma unroll
    for (int t = 0; t < 2; ++t) {
      int u = t * 256 + tid;
      int r = u >> 3, c8 = u & 7;
      int ra = m0 + r; if (ra >= M) ra = M - 1;
      *(u16x8*)&As[r][c8 * 8] = *(const u16x8*)(Ause + (size_t)ra * K + k0 + c8 * 8);
      *(u16x8*)&Ws[r][c8 * 8] = *(const u16x8*)(W + (size_t)(n0 + r) * K + k0 + c8 * 8);
    }
    __syncthreads();
#pragma unroll
    for (int ks = 0; ks < 64; ks += 32) {
      bf16x8 af[2], wf[2];
#pragma unroll
      for (int fr = 0; fr < 2; ++fr)
        af[fr] = *(const bf16x8*)&As[wm * 32 + fr * 16 + l15][ks + l4 * 8];
#pragma unroll
      for (int fn = 0; fn < 2; ++fn)
        wf[fn] = *(const bf16x8*)&Ws[wn * 32 + fn * 16 + l15][ks + l4 * 8];
#pragma unroll
      for (int fr = 0; fr < 2; ++fr)
#pragma unroll
        for (int fn = 0; fn < 2; ++fn)
          acc[fr][fn] = __builtin_amdgcn_mfma_f32_16x16x32_bf16(
              af[fr], wf[fn], acc[fr][fn], 0, 0, 0);
    }
    __syncthreads();
  }
#pragma unroll
  for (int fr = 0; fr < 2; ++fr)
#pragma unroll
    for (int fn = 0; fn < 2; ++fn) {
      int col = n0 + wn * 32 + fn * 16 + l15;
      float bs = bias[col];
#pragma unroll
      for (int j = 0; j < 4; ++j) {
        int row = m0 + wm * 32 + fr * 16 + l4 * 4 + j;
        if (row >= M) continue;
        float v = acc[fr][fn][j] + bs;
        if (relu) v = fmaxf(v, 0.f);
        if (outf) outf[(size_t)row * ldo + col] = v;
        if (outb) outb[(size_t)row * ldo + col] = f2b(v);
      }
    }
}

// ---------------------------------------------------------------- fused GEMM(N=256)+residual+LN, 16-row tiles
// y = LN(res + A@W^T + bias); outf f32 (may alias res); outb = bf16(y);
// qposb = bf16(y + qpos) (optional).
__global__ __launch_bounds__(256) void gemm_lnres_k(const unsigned short* __restrict__ A,
                                                    const unsigned short* __restrict__ W,
                                                    const float* __restrict__ bias,
                                                    const float* __restrict__ res,
                                                    const float* __restrict__ lnw,
                                                    const float* __restrict__ lnb,
                                                    const float* __restrict__ qpos,
                                                    float* __restrict__ outf,
                                                    unsigned short* __restrict__ outb,
                                                    unsigned short* __restrict__ qposb,
                                                    int M, int K) {
  __shared__ unsigned short As[16][72];
  __shared__ unsigned short Ws[256][72];
  __shared__ float Os[16][264];
  const int tid = threadIdx.x;
  const int lane = tid & 63, wv = tid >> 6;
  const int l15 = lane & 15, l4 = lane >> 4;
  const int m0 = blockIdx.x * 16;

  f32x4 acc[4] = {};
  for (int k0 = 0; k0 < K; k0 += 64) {
    if (tid < 128) {
      int r = tid >> 3, c8 = tid & 7;
      int ra = m0 + r; if (ra >= M) ra = M - 1;
      *(u16x8*)&As[r][c8 * 8] = *(const u16x8*)(A + (size_t)ra * K + k0 + c8 * 8);
    }
#pragma unroll
    for (int t = 0; t < 8; ++t) {
      int u = t * 256 + tid;
      int wr = u >> 3, wc = u & 7;
      *(u16x8*)&Ws[wr][wc * 8] = *(const u16x8*)(W + (size_t)wr * K + k0 + wc * 8);
    }
    __syncthreads();
#pragma unroll
    for (int ks = 0; ks < 64; ks += 32) {
      bf16x8 af = *(const bf16x8*)&As[l15][ks + l4 * 8];
#pragma unroll
      for (int fc = 0; fc < 4; ++fc) {
        bf16x8 wf = *(const bf16x8*)&Ws[wv * 64 + fc * 16 + l15][ks + l4 * 8];
        acc[fc] = __builtin_amdgcn_mfma_f32_16x16x32_bf16(af, wf, acc[fc], 0, 0, 0);
      }
    }
    __syncthreads();
  }
  // epilogue: bias + residual -> LDS
#pragma unroll
  for (int fc = 0; fc < 4; ++fc) {
    int col = wv * 64 + fc * 16 + l15;
    float bs = bias[col];
#pragma unroll
    for (int j = 0; j < 4; ++j) {
      int row = l4 * 4 + j;
      int grow = m0 + row;
      Os[row][col] = acc[fc][j] + bs + (grow < M ? res[(size_t)grow * 256 + col] : 0.f);
    }
  }
  __syncthreads();
  // LayerNorm: wave wv handles rows wv*4 .. wv*4+3
  float4 wv4 = *(const float4*)(lnw + lane * 4);
  float4 bv4 = *(const float4*)(lnb + lane * 4);
#pragma unroll
  for (int i = 0; i < 4; ++i) {
    int row = wv * 4 + i;
    int grow = m0 + row;
    float4 x = *(float4*)&Os[row][lane * 4];
    float s = x.x + x.y + x.z + x.w;
#pragma unroll
    for (int m = 1; m < 64; m <<= 1) s += __shfl_xor(s, m);
    const float mu = s * (1.f / DMODEL);
    float4 v = {x.x - mu, x.y - mu, x.z - mu, x.w - mu};
    float q = v.x * v.x + v.y * v.y + v.z * v.z + v.w * v.w;
#pragma unroll
    for (int m = 1; m < 64; m <<= 1) q += __shfl_xor(q, m);
    const float rstd = rsqrtf(q * (1.f / DMODEL) + EPS_LN);
    float4 y = {v.x * rstd * wv4.x + bv4.x, v.y * rstd * wv4.y + bv4.y,
                v.z * rstd * wv4.z + bv4.z, v.w * rstd * wv4.w + bv4.w};
    if (grow < M) {
      *(float4*)(outf + (size_t)grow * 256 + lane * 4) = y;
      if (outb) {
        u16x4 ob = {f2b(y.x), f2b(y.y), f2b(y.z), f2b(y.w)};
        *(u16x4*)(outb + (size_t)grow * 256 + lane * 4) = ob;
      }
      if (qposb) {
        float4 qv = *(const float4*)(qpos + (size_t)grow * 256 + lane * 4);
        u16x4 ob = {f2b(y.x + qv.x), f2b(y.y + qv.y), f2b(y.z + qv.z), f2b(y.w + qv.w)};
        *(u16x4*)(qposb + (size_t)grow * 256 + lane * 4) = ob;
      }
    }
  }
}

// ---------------------------------------------------------------- bf16 MFMA GEMM (value proj, 128x128)
__global__ __launch_bounds__(256) void gemm_vmfma_k(const unsigned short* __restrict__ A,
                                                    const unsigned short* __restrict__ W,
                                                    const float* __restrict__ bias,
                                                    unsigned short* __restrict__ C,
                                                    int M) {
  __shared__ unsigned short As[128][72];
  __shared__ unsigned short Ws[128][72];
  const int tid = threadIdx.x;
  const int lane = tid & 63, wv = tid >> 6;
  const int wm = wv >> 1, wn = wv & 1;
  const int m0 = blockIdx.x * 128, n0 = blockIdx.y * 128;
  const int l15 = lane & 15, l4 = lane >> 4;

  f32x4 acc[4][4] = {};

  for (int k0 = 0; k0 < 256; k0 += 64) {
#pragma unroll
    for (int t = 0; t < 4; ++t) {
      int u = t * 256 + tid;
      int r = u >> 3, c8 = u & 7;
      int ra = m0 + r; if (ra >= M) ra = M - 1;
      *(u16x8*)&As[r][c8 * 8] = *(const u16x8*)(A + (size_t)ra * 256 + k0 + c8 * 8);
      *(u16x8*)&Ws[r][c8 * 8] = *(const u16x8*)(W + (size_t)(n0 + r) * 256 + k0 + c8 * 8);
    }
    __syncthreads();
#pragma unroll
    for (int ks = 0; ks < 64; ks += 32) {
      bf16x8 af[4], bf[4];
#pragma unroll
      for (int fr = 0; fr < 4; ++fr)
        af[fr] = *(const bf16x8*)&As[wm * 64 + fr * 16 + l15][ks + l4 * 8];
#pragma unroll
      for (int fn = 0; fn < 4; ++fn)
        bf[fn] = *(const bf16x8*)&Ws[wn * 64 + fn * 16 + l15][ks + l4 * 8];
#pragma unroll
      for (int fr = 0; fr < 4; ++fr)
#pragma unroll
        for (int fn = 0; fn < 4; ++fn)
          acc[fr][fn] = __builtin_amdgcn_mfma_f32_16x16x32_bf16(
              af[fr], bf[fn], acc[fr][fn], 0, 0, 0);
    }
    __syncthreads();
  }
#pragma unroll
  for (int fr = 0; fr < 4; ++fr)
#pragma unroll
    for (int fn = 0; fn < 4; ++fn) {
      int col = n0 + wn * 64 + fn * 16 + l15;
      float bs = bias[col];
#pragma unroll
      for (int j = 0; j < 4; ++j) {
        int row = m0 + wm * 64 + fr * 16 + l4 * 4 + j;
        if (row < M) C[(size_t)row * 256 + col] = f2b(acc[fr][fn][j] + bs);
      }
    }
}

// ---------------------------------------------------------------- MFMA flash self-attn
__global__ __launch_bounds__(256) void fattn_mfma_k(const unsigned short* __restrict__ qkv,
                                                    unsigned short* __restrict__ o) {
  __shared__ unsigned short Qlds[64][40];
  __shared__ unsigned short Klds[64][40];
  __shared__ unsigned short Vt[32][72];   // V transposed [dh][key]
  __shared__ unsigned short Plds[64][72];
  const int tid = threadIdx.x;
  const int lane = tid & 63;
  const int wq = tid >> 6;
  const int l15 = lane & 15, l4 = lane >> 4;
  const int q0 = blockIdx.x * 64;
  const int h = blockIdx.y, b = blockIdx.z;
  const int hq = h * 32;
  const size_t rowb = (size_t)b * NQ;

  {
    int q = q0 + (tid >> 2);
    int qc = q < NQ ? q : NQ - 1;
    *(u16x8*)&Qlds[tid >> 2][(tid & 3) * 8] =
        *(const u16x8*)(qkv + (rowb + qc) * 768 + hq + (tid & 3) * 8);
  }
  __syncthreads();
  const bf16x8 qf = *(const bf16x8*)&Qlds[wq * 16 + l15][l4 * 8];

  float m_r[4] = {-1e30f, -1e30f, -1e30f, -1e30f};
  float l_r[4] = {0.f, 0.f, 0.f, 0.f};
  f32x4 oacc[2] = {};

  for (int k0 = 0; k0 < NQ; k0 += 64) {
    __syncthreads();
    {
      int kk = k0 + (tid >> 2);
      int kc = kk < NQ ? kk : NQ - 1;
      const unsigned short* kbase = qkv + (rowb + kc) * 768 + hq + (tid & 3) * 8;
      u16x8 kv = *(const u16x8*)(kbase + 256);
      u16x8 vv = *(const u16x8*)(kbase + 512);
      *(u16x8*)&Klds[tid >> 2][(tid & 3) * 8] = kv;
#pragma unroll
      for (int i = 0; i < 8; ++i) Vt[(tid & 3) * 8 + i][tid >> 2] = vv[i];
    }
    __syncthreads();

    f32x4 s[4];
#pragma unroll
    for (int fc = 0; fc < 4; ++fc) {
      bf16x8 kf = *(const bf16x8*)&Klds[fc * 16 + l15][l4 * 8];
      s[fc] = __builtin_amdgcn_mfma_f32_16x16x32_bf16(qf, kf, (f32x4){0.f, 0.f, 0.f, 0.f}, 0, 0, 0);
    }
#pragma unroll
    for (int fc = 0; fc < 4; ++fc) {
      bool oob = (k0 + fc * 16 + l15) >= NQ;
#pragma unroll
      for (int j = 0; j < 4; ++j)
        s[fc][j] = oob ? -1e30f : s[fc][j] * ATT_SCALE;
    }
#pragma unroll
    for (int j = 0; j < 4; ++j) {
      float tm = fmaxf(fmaxf(s[0][j], s[1][j]), fmaxf(s[2][j], s[3][j]));
      tm = fmaxf(tm, __shfl_xor(tm, 1, 16));
      tm = fmaxf(tm, __shfl_xor(tm, 2, 16));
      tm = fmaxf(tm, __shfl_xor(tm, 4, 16));
      tm = fmaxf(tm, __shfl_xor(tm, 8, 16));
      float mn = fmaxf(m_r[j], tm);
      float sf = __expf(m_r[j] - mn);
      m_r[j] = mn;
      oacc[0][j] *= sf;
      oacc[1][j] *= sf;
      float rs = 0.f;
#pragma unroll
      for (int fc = 0; fc < 4; ++fc) {
        float pv = __expf(s[fc][j] - mn);
        s[fc][j] = pv;
        rs += pv;
      }
      rs += __shfl_xor(rs, 1, 16);
      rs += __shfl_xor(rs, 2, 16);
      rs += __shfl_xor(rs, 4, 16);
      rs += __shfl_xor(rs, 8, 16);
      l_r[j] = l_r[j] * sf + rs;
    }
#pragma unroll
    for (int fc = 0; fc < 4; ++fc)
#pragma unroll
      for (int j = 0; j < 4; ++j)
        Plds[wq * 16 + l4 * 4 + j][fc * 16 + l15] = f2b(s[fc][j]);
    __syncthreads();
#pragma unroll
    for (int ks = 0; ks < 2; ++ks) {
      bf16x8 pf = *(const bf16x8*)&Plds[wq * 16 + l15][ks * 32 + l4 * 8];
#pragma unroll
      for (int oc = 0; oc < 2; ++oc) {
        bf16x8 vf = *(const bf16x8*)&Vt[oc * 16 + l15][ks * 32 + l4 * 8];
        oacc[oc] = __builtin_amdgcn_mfma_f32_16x16x32_bf16(pf, vf, oacc[oc], 0, 0, 0);
      }
    }
  }
#pragma unroll
  for (int j = 0; j < 4; ++j) {
    int q = q0 + wq * 16 + l4 * 4 + j;
    if (q < NQ) {
      float inv = 1.f / l_r[j];
      o[(rowb + q) * 256 + hq + l15] = f2b(oacc[0][j] * inv);
      o[(rowb + q) * 256 + hq + 16 + l15] = f2b(oacc[1][j] * inv);
    }
  }
}

// ---------------------------------------------------------------- MSDA sample
__global__ __launch_bounds__(256) void msda_k(const float* __restrict__ refp,
                                              const float* __restrict__ vr,
                                              const unsigned short* __restrict__ value,
                                              const float* __restrict__ cat,
                                              unsigned short* __restrict__ outp) {
  const int HW[4][2] = {{92, 160}, {46, 80}, {23, 40}, {12, 20}};
  const int START[4] = {0, 14720, 18400, 19320};
  const int qi = blockIdx.x, b = blockIdx.y;
  const int tid = threadIdx.x;
  const int h = tid >> 5;
  const int r = tid & 31;
  const int lvl = r >> 3;
  const int li = r & 7;
  const size_t base = (size_t)(b * NQ + qi);
  const float rx = refp[base * 3 + 0];
  const float rz = refp[base * 3 + 2];

  const float* lg = cat + base * 384 + 256 + h * 16;
  float4 L0 = *(const float4*)(lg + 0);
  float4 L1 = *(const float4*)(lg + 4);
  float4 L2 = *(const float4*)(lg + 8);
  float4 L3 = *(const float4*)(lg + 12);
  float mx = fmaxf(fmaxf(fmaxf(L0.x, L0.y), fmaxf(L0.z, L0.w)),
                   fmaxf(fmaxf(fmaxf(L1.x, L1.y), fmaxf(L1.z, L1.w)),
                         fmaxf(fmaxf(fmaxf(L2.x, L2.y), fmaxf(L2.z, L2.w)),
                               fmaxf(fmaxf(L3.x, L3.y), fmaxf(L3.z, L3.w)))));
  float4 E0 = {__expf(L0.x - mx), __expf(L0.y - mx), __expf(L0.z - mx), __expf(L0.w - mx)};
  float4 E1 = {__expf(L1.x - mx), __expf(L1.y - mx), __expf(L1.z - mx), __expf(L1.w - mx)};
  float4 E2 = {__expf(L2.x - mx), __expf(L2.y - mx), __expf(L2.z - mx), __expf(L2.w - mx)};
  float4 E3 = {__expf(L3.x - mx), __expf(L3.y - mx), __expf(L3.z - mx), __expf(L3.w - mx)};
  float sum = E0.x + E0.y + E0.z + E0.w + E1.x + E1.y + E1.z + E1.w +
              E2.x + E2.y + E2.z + E2.w + E3.x + E3.y + E3.z + E3.w;
  const float inv = 1.f / sum;
  float4 Emy = lvl == 0 ? E0 : lvl == 1 ? E1 : lvl == 2 ? E2 : E3;
  float wl[4] = {Emy.x * inv, Emy.y * inv, Emy.z * inv, Emy.w * inv};

  const int H = HW[lvl][0], W = HW[lvl][1];
  const float refx = rx * vr[(b * LEVELS + lvl) * 2 + 0] * (float)W;
  const float refy = rz * vr[(b * LEVELS + lvl) * 2 + 1] * (float)H;
  const unsigned short* vbase = value + ((size_t)b * SLEN + START[lvl]) * DMODEL + h * DHEAD + li * 4;
  const float* ob = cat + base * 384 + h * 32 + lvl * 8;

  float a0 = 0.f, a1 = 0.f, a2 = 0.f, a3 = 0.f;
#pragma unroll
  for (int p = 0; p < 4; ++p) {
    const float x = refx + ob[p * 2 + 0] - 0.5f;
    const float y = refy + ob[p * 2 + 1] - 0.5f;
    const float x0f = floorf(x), y0f = floorf(y);
    const float fx = x - x0f, fy = y - y0f;
    const int x0 = (int)x0f, y0 = (int)y0f;
#pragma unroll
    for (int ci = 0; ci < 4; ++ci) {
      const int xi = x0 + (ci & 1);
      const int yi = y0 + (ci >> 1);
      if ((xi >= 0) && (xi < W) && (yi >= 0) && (yi < H)) {
        const float wxy = ((ci & 1) ? fx : 1.f - fx) * ((ci >> 1) ? fy : 1.f - fy) * wl[p];
        u16x4 v4 = *(const u16x4*)(vbase + (size_t)(yi * W + xi) * DMODEL);
        a0 = fmaf(wxy, b2f(v4[0]), a0);
        a1 = fmaf(wxy, b2f(v4[1]), a1);
        a2 = fmaf(wxy, b2f(v4[2]), a2);
        a3 = fmaf(wxy, b2f(v4[3]), a3);
      }
    }
  }
  a0 += __shfl_xor(a0, 8);  a1 += __shfl_xor(a1, 8);
  a2 += __shfl_xor(a2, 8);  a3 += __shfl_xor(a3, 8);
  a0 += __shfl_xor(a0, 16); a1 += __shfl_xor(a1, 16);
  a2 += __shfl_xor(a2, 16); a3 += __shfl_xor(a3, 16);
  if (lvl == 0) {
    u16x4 o4 = {f2b(a0), f2b(a1), f2b(a2), f2b(a3)};
    *(u16x4*)(outp + base * 256 + h * 32 + li * 4) = o4;
  }
}

// ---------------------------------------------------------------- launcher
extern "C" void kernel_launch(void* const* d_in, const int* in_sizes, int n_in,
                              void* d_out, int out_size, void* d_ws, size_t ws_size,
                              hipStream_t stream) {
  const float* tgt     = (const float*)d_in[0];
  const float* refp    = (const float*)d_in[1];
  const float* src     = (const float*)d_in[2];
  const float* vr      = (const float*)d_in[3];
  const float* qpos    = (const float*)d_in[4];
  const float* sa_in_w = (const float*)d_in[5];
  const float* sa_in_b = (const float*)d_in[6];
  const float* sa_out_w= (const float*)d_in[7];
  const float* sa_out_b= (const float*)d_in[8];
  const float* samp_w  = (const float*)d_in[9];
  const float* samp_b  = (const float*)d_in[10];
  const float* attn_w  = (const float*)d_in[11];
  const float* attn_b  = (const float*)d_in[12];
  const float* val_w   = (const float*)d_in[13];
  const float* val_b   = (const float*)d_in[14];
  const float* ca_out_w= (const float*)d_in[15];
  const float* ca_out_b= (const float*)d_in[16];
  const float* ffn1_w  = (const float*)d_in[17];
  const float* ffn1_b  = (const float*)d_in[18];
  const float* ffn2_w  = (const float*)d_in[19];
  const float* ffn2_b  = (const float*)d_in[20];
  const float* ln1_w   = (const float*)d_in[21];
  const float* ln1_b   = (const float*)d_in[22];
  const float* ln2_w   = (const float*)d_in[23];
  const float* ln2_b   = (const float*)d_in[24];
  const float* ln3_w   = (const float*)d_in[25];
  const float* ln3_b   = (const float*)d_in[26];

  const int M = BS * NQ;                 // 3600
  const int MV = BS * SLEN;              // 78240
  const size_t TOK = (size_t)M * DMODEL; // 921600

  float* ws = (float*)d_ws;
  size_t off = 0;
  auto alloc = [&](size_t n) { float* p = ws + off; off += n; return p; };
  auto allocb = [&](size_t n) { unsigned short* p = (unsigned short*)(ws + off); off += (n + 1) / 2; return p; };
  float* cur     = alloc(TOK);
  float* catout  = alloc((size_t)M * 384);
  float* b_cacat = alloc((size_t)NLAYERS * 384);
  unsigned short* cur_bf  = allocb(TOK);
  unsigned short* qbuf_bf = allocb(TOK);
  unsigned short* sao_bf  = allocb(TOK);
  unsigned short* msda_bf = allocb(TOK);
  unsigned short* qkv_bf  = allocb((size_t)M * 768);
  unsigned short* ffnh_bf = allocb((size_t)M * DFF);
  unsigned short* src_bf  = allocb((size_t)MV * DMODEL);
  unsigned short* value_bf= allocb((size_t)MV * DMODEL);
  unsigned short* w_in_bf   = allocb((size_t)NLAYERS * 768 * 256);
  unsigned short* w_saout_bf= allocb((size_t)NLAYERS * 256 * 256);
  unsigned short* w_cacat_bf= allocb((size_t)NLAYERS * 384 * 256);
  unsigned short* w_val_bf  = allocb((size_t)NLAYERS * 256 * 256);
  unsigned short* w_caout_bf= allocb((size_t)NLAYERS * 256 * 256);
  unsigned short* w_ffn1_bf = allocb((size_t)NLAYERS * DFF * 256);
  unsigned short* w_ffn2_bf = allocb((size_t)NLAYERS * 256 * DFF);

  const int n4 = (int)(TOK / 4);
  const dim3 blk(256);
  const dim3 gE((n4 + 255) / 256);

  // prologue
  copycvt_k<<<gE, blk, 0, stream>>>(tgt, qpos, cur, cur_bf, qbuf_bf, n4);
  f2ball_k<<<dim3(2048), blk, 0, stream>>>(src, sa_in_w, sa_out_w, val_w, ca_out_w,
                                           ffn1_w, ffn2_w,
                                           src_bf, w_in_bf, w_saout_bf, w_val_bf,
                                           w_caout_bf, w_ffn1_bf, w_ffn2_bf);
  catw_k<<<dim3(576), blk, 0, stream>>>(samp_w, attn_w, samp_b, attn_b, w_cacat_bf, b_cacat);

  const int BIG = 1 << 30;
  const dim3 gQKV(57, 12);   // N=768
  const dim3 gCat(57, 6);    // N=384
  const dim3 gF1(57, 16);    // N=1024
  const dim3 gLN(225);       // fused gemm+LN, 16-row tiles

  for (int l = 0; l < NLAYERS; ++l) {
    // QKV: cols<512 (q,k) read qbuf (cur+qpos); cols>=512 (v) read cur
    gemm_bf_k<<<gQKV, blk, 0, stream>>>(qbuf_bf, cur_bf, 512,
                                        w_in_bf + (size_t)l * 768 * 256,
                                        sa_in_b + l * 768,
                                        nullptr, qkv_bf, 768, M, 768, 256, 0);

    fattn_mfma_k<<<dim3((NQ + 63) / 64, HEADS, BS), blk, 0, stream>>>(qkv_bf, sao_bf);

    gemm_lnres_k<<<gLN, blk, 0, stream>>>(sao_bf, w_saout_bf + (size_t)l * 256 * 256,
                                          sa_out_b + l * 256, cur,
                                          ln1_w + l * 256, ln1_b + l * 256, qpos,
                                          cur, nullptr, qbuf_bf, M, 256);

    // cross-attn (MSDA)
    gemm_vmfma_k<<<dim3((MV + 127) / 128, 2), blk, 0, stream>>>(
        src_bf, w_val_bf + (size_t)l * 256 * 256, val_b + l * 256, value_bf, MV);
    gemm_bf_k<<<gCat, blk, 0, stream>>>(qbuf_bf, qbuf_bf, BIG,
                                        w_cacat_bf + (size_t)l * 384 * 256,
                                        b_cacat + l * 384,
                                        catout, nullptr, 384, M, 384, 256, 0);

    msda_k<<<dim3(NQ, BS), blk, 0, stream>>>(refp, vr, value_bf, catout, msda_bf);

    gemm_lnres_k<<<gLN, blk, 0, stream>>>(msda_bf, w_caout_bf + (size_t)l * 256 * 256,
                                          ca_out_b + l * 256, cur,
                                          ln2_w + l * 256, ln2_b + l * 256, nullptr,
                                          cur, cur_bf, nullptr, M, 256);

    // FFN
    gemm_bf_k<<<gF1, blk, 0, stream>>>(cur_bf, cur_bf, BIG,
                                       w_ffn1_bf + (size_t)l * DFF * 256,
                                       ffn1_b + l * DFF,
                                       nullptr, ffnh_bf, DFF, M, DFF, 256, 1);
    const bool last = (l == NLAYERS - 1);
    gemm_lnres_k<<<gLN, blk, 0, stream>>>(ffnh_bf, w_ffn2_bf + (size_t)l * 256 * DFF,
                                          ffn2_b + l * 256, cur,
                                          ln3_w + l * 256, ln3_b + l * 256,
                                          last ? nullptr : qpos,
                                          last ? (float*)d_out : cur,
                                          last ? nullptr : cur_bf,
                                          last ? nullptr : qbuf_bf, M, DFF);
  }
}

// Round 9
// 1166.183 us; speedup vs baseline: 1.2061x; 1.0513x over previous
//
#include <hip/hip_runtime.h>
#include <math.h>

#define DMODEL 256
#define HEADS 8
#define DHEAD 32
#define LEVELS 4
#define POINTS 4
#define NLAYERS 6
#define DFF 1024
#define BS 4
#define NQ 900
#define SLEN 19560
#define EPS_LN 1e-5f
#define ATT_SCALE 0.17677669529663689f

typedef __attribute__((ext_vector_type(8))) short bf16x8;
typedef __attribute__((ext_vector_type(4))) float f32x4;
typedef __attribute__((ext_vector_type(4))) unsigned short u16x4;
typedef __attribute__((ext_vector_type(8))) unsigned short u16x8;

__device__ __forceinline__ unsigned short f2b(float x) {
  unsigned u = __float_as_uint(x);
  u += 0x7FFF + ((u >> 16) & 1);
  return (unsigned short)(u >> 16);
}
__device__ __forceinline__ float b2f(unsigned short v) {
  return __uint_as_float(((unsigned)v) << 16);
}

// async global->LDS, 16B per lane; lds dest = wave-uniform base + lane*16
__device__ __forceinline__ void gload16(const void* g, void* l) {
  __builtin_amdgcn_global_load_lds(
      (const __attribute__((address_space(1))) void*)g,
      (__attribute__((address_space(3))) void*)l, 16, 0, 0);
}

// ---------------------------------------------------------------- prologue elementwise
__global__ __launch_bounds__(256) void copycvt_k(const float* __restrict__ a,
                                                 const float* __restrict__ qp,
                                                 float* __restrict__ cf,
                                                 unsigned short* __restrict__ cb,
                                                 unsigned short* __restrict__ qb, int n4) {
  int i = blockIdx.x * 256 + threadIdx.x;
  if (i < n4) {
    float4 v = reinterpret_cast<const float4*>(a)[i];
    float4 q = reinterpret_cast<const float4*>(qp)[i];
    reinterpret_cast<float4*>(cf)[i] = v;
    u16x4 o4 = {f2b(v.x), f2b(v.y), f2b(v.z), f2b(v.w)};
    reinterpret_cast<u16x4*>(cb)[i] = o4;
    u16x4 p4 = {f2b(v.x + q.x), f2b(v.y + q.y), f2b(v.z + q.z), f2b(v.w + q.w)};
    reinterpret_cast<u16x4*>(qb)[i] = p4;
  }
}

#define N4_SRC (SLEN * BS * DMODEL / 4)
#define N4_SAIN (NLAYERS * 768 * 256 / 4)
#define N4_SQ (NLAYERS * 256 * 256 / 4)
#define N4_FFN (NLAYERS * DFF * 256 / 4)
__global__ __launch_bounds__(256) void f2ball_k(
    const float* __restrict__ s0, const float* __restrict__ s1,
    const float* __restrict__ s2, const float* __restrict__ s3,
    const float* __restrict__ s4, const float* __restrict__ s5,
    const float* __restrict__ s6,
    unsigned short* __restrict__ d0, unsigned short* __restrict__ d1,
    unsigned short* __restrict__ d2, unsigned short* __restrict__ d3,
    unsigned short* __restrict__ d4, unsigned short* __restrict__ d5,
    unsigned short* __restrict__ d6) {
  const int total = N4_SRC + N4_SAIN + 3 * N4_SQ + 2 * N4_FFN;
  for (int i = blockIdx.x * 256 + threadIdx.x; i < total; i += gridDim.x * 256) {
    const float* s;
    unsigned short* d;
    int j = i;
    if (j < N4_SRC) { s = s0; d = d0; }
    else { j -= N4_SRC;
      if (j < N4_SAIN) { s = s1; d = d1; }
      else { j -= N4_SAIN;
        if (j < N4_SQ) { s = s2; d = d2; }
        else { j -= N4_SQ;
          if (j < N4_SQ) { s = s3; d = d3; }
          else { j -= N4_SQ;
            if (j < N4_SQ) { s = s4; d = d4; }
            else { j -= N4_SQ;
              if (j < N4_FFN) { s = s5; d = d5; }
              else { j -= N4_FFN; s = s6; d = d6; } } } } } }
    float4 v = reinterpret_cast<const float4*>(s)[j];
    u16x4 o4 = {f2b(v.x), f2b(v.y), f2b(v.z), f2b(v.w)};
    reinterpret_cast<u16x4*>(d)[j] = o4;
  }
}

__global__ __launch_bounds__(256) void catw_k(const float* __restrict__ sw,
                                              const float* __restrict__ aw,
                                              const float* __restrict__ sb,
                                              const float* __restrict__ ab,
                                              unsigned short* __restrict__ wout,
                                              float* __restrict__ bout) {
  int i = blockIdx.x * 256 + threadIdx.x;
  const int total4 = NLAYERS * 384 * 256 / 4;
  if (i < total4) {
    int l = i / (384 * 64);
    int r = i % (384 * 64);
    int row = r / 64;
    int c4 = r % 64;
    const float* srcp = row < 256
        ? sw + ((size_t)l * 256 * 256 + (size_t)row * 256 + c4 * 4)
        : aw + ((size_t)l * 128 * 256 + (size_t)(row - 256) * 256 + c4 * 4);
    float4 v = *(const float4*)srcp;
    u16x4 o4 = {f2b(v.x), f2b(v.y), f2b(v.z), f2b(v.w)};
    *(u16x4*)(wout + (size_t)i * 4) = o4;
  }
  if (i < NLAYERS * 384) {
    int l = i / 384, r = i % 384;
    bout[i] = r < 256 ? sb[l * 256 + r] : ab[l * 128 + (r - 256)];
  }
}

// ---------------------------------------------------------------- bf16 MFMA GEMM, 64x64 tile, gload_lds staging
// out[M,N](ld=ldo) = Ause[M,K] @ W[N,K]^T + bias; Ause = (n0>=nsplit) ? A2 : A.
__global__ __launch_bounds__(256) void gemm_bf_k(const unsigned short* __restrict__ A,
                                                 const unsigned short* __restrict__ A2,
                                                 int nsplit,
                                                 const unsigned short* __restrict__ W,
                                                 const float* __restrict__ bias,
                                                 float* __restrict__ outf,
                                                 unsigned short* __restrict__ outb,
                                                 int ldo, int M, int N, int K, int relu) {
  __shared__ unsigned short As[64][64];
  __shared__ unsigned short Ws[64][64];
  const int tid = threadIdx.x;
  const int lane = tid & 63, wv = tid >> 6;
  const int wm = wv >> 1, wn = wv & 1;
  const int m0 = blockIdx.x * 64, n0 = blockIdx.y * 64;
  const int l15 = lane & 15, l4 = lane >> 4;
  const unsigned short* __restrict__ Ause = (n0 >= nsplit) ? A2 : A;
  const int lr = lane >> 3, lc = lane & 7;

  f32x4 acc[2][2] = {};
  for (int k0 = 0; k0 < K; k0 += 64) {
#pragma unroll
    for (int t = 0; t < 2; ++t) {
      int c = wv * 2 + t;            // 8 chunks of 8 rows
      int r = c * 8 + lr;
      int ra = m0 + r; if (ra >= M) ra = M - 1;
      gload16(Ause + (size_t)ra * K + k0 + lc * 8, ((char*)As) + c * 1024);
      gload16(W + (size_t)(n0 + r) * K + k0 + lc * 8, ((char*)Ws) + c * 1024);
    }
    __syncthreads();
#pragma unroll
    for (int ks = 0; ks < 64; ks += 32) {
      bf16x8 af[2], wf[2];
#pragma unroll
      for (int fr = 0; fr < 2; ++fr)
        af[fr] = *(const bf16x8*)&As[wm * 32 + fr * 16 + l15][ks + l4 * 8];
#pragma unroll
      for (int fn = 0; fn < 2; ++fn)
        wf[fn] = *(const bf16x8*)&Ws[wn * 32 + fn * 16 + l15][ks + l4 * 8];
#pragma unroll
      for (int fr = 0; fr < 2; ++fr)
#pragma unroll
        for (int fn = 0; fn < 2; ++fn)
          acc[fr][fn] = __builtin_amdgcn_mfma_f32_16x16x32_bf16(
              af[fr], wf[fn], acc[fr][fn], 0, 0, 0);
    }
    __syncthreads();
  }
#pragma unroll
  for (int fr = 0; fr < 2; ++fr)
#pragma unroll
    for (int fn = 0; fn < 2; ++fn) {
      int col = n0 + wn * 32 + fn * 16 + l15;
      float bs = bias[col];
#pragma unroll
      for (int j = 0; j < 4; ++j) {
        int row = m0 + wm * 32 + fr * 16 + l4 * 4 + j;
        if (row >= M) continue;
        float v = acc[fr][fn][j] + bs;
        if (relu) v = fmaxf(v, 0.f);
        if (outf) outf[(size_t)row * ldo + col] = v;
        if (outb) outb[(size_t)row * ldo + col] = f2b(v);
      }
    }
}

// ---------------------------------------------------------------- fused GEMM(N=256)+residual+LN, 16-row tiles
__global__ __launch_bounds__(256) void gemm_lnres_k(const unsigned short* __restrict__ A,
                                                    const unsigned short* __restrict__ W,
                                                    const float* __restrict__ bias,
                                                    const float* __restrict__ res,
                                                    const float* __restrict__ lnw,
                                                    const float* __restrict__ lnb,
                                                    const float* __restrict__ qpos,
                                                    float* __restrict__ outf,
                                                    unsigned short* __restrict__ outb,
                                                    unsigned short* __restrict__ qposb,
                                                    int M, int K) {
  __shared__ unsigned short As[16][72];
  __shared__ unsigned short Ws[256][64];
  __shared__ float Os[16][264];
  const int tid = threadIdx.x;
  const int lane = tid & 63, wv = tid >> 6;
  const int l15 = lane & 15, l4 = lane >> 4;
  const int m0 = blockIdx.x * 16;
  const int lr = lane >> 3, lc = lane & 7;

  f32x4 acc[4] = {};
  for (int k0 = 0; k0 < K; k0 += 64) {
    if (tid < 128) {
      int r = tid >> 3, c8 = tid & 7;
      int ra = m0 + r; if (ra >= M) ra = M - 1;
      *(u16x8*)&As[r][c8 * 8] = *(const u16x8*)(A + (size_t)ra * K + k0 + c8 * 8);
    }
#pragma unroll
    for (int t = 0; t < 8; ++t) {
      int c = wv * 8 + t;            // 32 chunks of 8 rows
      int r = c * 8 + lr;            // 0..255
      gload16(W + (size_t)r * K + k0 + lc * 8, ((char*)Ws) + c * 1024);
    }
    __syncthreads();
#pragma unroll
    for (int ks = 0; ks < 64; ks += 32) {
      bf16x8 af = *(const bf16x8*)&As[l15][ks + l4 * 8];
#pragma unroll
      for (int fc = 0; fc < 4; ++fc) {
        bf16x8 wf = *(const bf16x8*)&Ws[wv * 64 + fc * 16 + l15][ks + l4 * 8];
        acc[fc] = __builtin_amdgcn_mfma_f32_16x16x32_bf16(af, wf, acc[fc], 0, 0, 0);
      }
    }
    __syncthreads();
  }
#pragma unroll
  for (int fc = 0; fc < 4; ++fc) {
    int col = wv * 64 + fc * 16 + l15;
    float bs = bias[col];
#pragma unroll
    for (int j = 0; j < 4; ++j) {
      int row = l4 * 4 + j;
      int grow = m0 + row;
      Os[row][col] = acc[fc][j] + bs + (grow < M ? res[(size_t)grow * 256 + col] : 0.f);
    }
  }
  __syncthreads();
  float4 wv4 = *(const float4*)(lnw + lane * 4);
  float4 bv4 = *(const float4*)(lnb + lane * 4);
#pragma unroll
  for (int i = 0; i < 4; ++i) {
    int row = wv * 4 + i;
    int grow = m0 + row;
    float4 x = *(float4*)&Os[row][lane * 4];
    float s = x.x + x.y + x.z + x.w;
#pragma unroll
    for (int m = 1; m < 64; m <<= 1) s += __shfl_xor(s, m);
    const float mu = s * (1.f / DMODEL);
    float4 v = {x.x - mu, x.y - mu, x.z - mu, x.w - mu};
    float q = v.x * v.x + v.y * v.y + v.z * v.z + v.w * v.w;
#pragma unroll
    for (int m = 1; m < 64; m <<= 1) q += __shfl_xor(q, m);
    const float rstd = rsqrtf(q * (1.f / DMODEL) + EPS_LN);
    float4 y = {v.x * rstd * wv4.x + bv4.x, v.y * rstd * wv4.y + bv4.y,
                v.z * rstd * wv4.z + bv4.z, v.w * rstd * wv4.w + bv4.w};
    if (grow < M) {
      *(float4*)(outf + (size_t)grow * 256 + lane * 4) = y;
      if (outb) {
        u16x4 ob = {f2b(y.x), f2b(y.y), f2b(y.z), f2b(y.w)};
        *(u16x4*)(outb + (size_t)grow * 256 + lane * 4) = ob;
      }
      if (qposb) {
        float4 qv = *(const float4*)(qpos + (size_t)grow * 256 + lane * 4);
        u16x4 ob = {f2b(y.x + qv.x), f2b(y.y + qv.y), f2b(y.z + qv.z), f2b(y.w + qv.w)};
        *(u16x4*)(qposb + (size_t)grow * 256 + lane * 4) = ob;
      }
    }
  }
}

// ---------------------------------------------------------------- bf16 MFMA GEMM (value proj, 128x128), gload_lds
__global__ __launch_bounds__(256) void gemm_vmfma_k(const unsigned short* __restrict__ A,
                                                    const unsigned short* __restrict__ W,
                                                    const float* __restrict__ bias,
                                                    unsigned short* __restrict__ C,
                                                    int M) {
  __shared__ unsigned short As[128][64];
  __shared__ unsigned short Ws[128][64];
  const int tid = threadIdx.x;
  const int lane = tid & 63, wv = tid >> 6;
  const int wm = wv >> 1, wn = wv & 1;
  const int m0 = blockIdx.x * 128, n0 = blockIdx.y * 128;
  const int l15 = lane & 15, l4 = lane >> 4;
  const int lr = lane >> 3, lc = lane & 7;

  f32x4 acc[4][4] = {};

  for (int k0 = 0; k0 < 256; k0 += 64) {
#pragma unroll
    for (int t = 0; t < 4; ++t) {
      int c = wv * 4 + t;            // 16 chunks of 8 rows
      int r = c * 8 + lr;            // 0..127
      int ra = m0 + r; if (ra >= M) ra = M - 1;
      gload16(A + (size_t)ra * 256 + k0 + lc * 8, ((char*)As) + c * 1024);
      gload16(W + (size_t)(n0 + r) * 256 + k0 + lc * 8, ((char*)Ws) + c * 1024);
    }
    __syncthreads();
#pragma unroll
    for (int ks = 0; ks < 64; ks += 32) {
      bf16x8 af[4], bf[4];
#pragma unroll
      for (int fr = 0; fr < 4; ++fr)
        af[fr] = *(const bf16x8*)&As[wm * 64 + fr * 16 + l15][ks + l4 * 8];
#pragma unroll
      for (int fn = 0; fn < 4; ++fn)
        bf[fn] = *(const bf16x8*)&Ws[wn * 64 + fn * 16 + l15][ks + l4 * 8];
#pragma unroll
      for (int fr = 0; fr < 4; ++fr)
#pragma unroll
        for (int fn = 0; fn < 4; ++fn)
          acc[fr][fn] = __builtin_amdgcn_mfma_f32_16x16x32_bf16(
              af[fr], bf[fn], acc[fr][fn], 0, 0, 0);
    }
    __syncthreads();
  }
#pragma unroll
  for (int fr = 0; fr < 4; ++fr)
#pragma unroll
    for (int fn = 0; fn < 4; ++fn) {
      int col = n0 + wn * 64 + fn * 16 + l15;
      float bs = bias[col];
#pragma unroll
      for (int j = 0; j < 4; ++j) {
        int row = m0 + wm * 64 + fr * 16 + l4 * 4 + j;
        if (row < M) C[(size_t)row * 256 + col] = f2b(acc[fr][fn][j] + bs);
      }
    }
}

// ---------------------------------------------------------------- MFMA flash self-attn (unchanged)
__global__ __launch_bounds__(256) void fattn_mfma_k(const unsigned short* __restrict__ qkv,
                                                    unsigned short* __restrict__ o) {
  __shared__ unsigned short Qlds[64][40];
  __shared__ unsigned short Klds[64][40];
  __shared__ unsigned short Vt[32][72];
  __shared__ unsigned short Plds[64][72];
  const int tid = threadIdx.x;
  const int lane = tid & 63;
  const int wq = tid >> 6;
  const int l15 = lane & 15, l4 = lane >> 4;
  const int q0 = blockIdx.x * 64;
  const int h = blockIdx.y, b = blockIdx.z;
  const int hq = h * 32;
  const size_t rowb = (size_t)b * NQ;

  {
    int q = q0 + (tid >> 2);
    int qc = q < NQ ? q : NQ - 1;
    *(u16x8*)&Qlds[tid >> 2][(tid & 3) * 8] =
        *(const u16x8*)(qkv + (rowb + qc) * 768 + hq + (tid & 3) * 8);
  }
  __syncthreads();
  const bf16x8 qf = *(const bf16x8*)&Qlds[wq * 16 + l15][l4 * 8];

  float m_r[4] = {-1e30f, -1e30f, -1e30f, -1e30f};
  float l_r[4] = {0.f, 0.f, 0.f, 0.f};
  f32x4 oacc[2] = {};

  for (int k0 = 0; k0 < NQ; k0 += 64) {
    __syncthreads();
    {
      int kk = k0 + (tid >> 2);
      int kc = kk < NQ ? kk : NQ - 1;
      const unsigned short* kbase = qkv + (rowb + kc) * 768 + hq + (tid & 3) * 8;
      u16x8 kv = *(const u16x8*)(kbase + 256);
      u16x8 vv = *(const u16x8*)(kbase + 512);
      *(u16x8*)&Klds[tid >> 2][(tid & 3) * 8] = kv;
#pragma unroll
      for (int i = 0; i < 8; ++i) Vt[(tid & 3) * 8 + i][tid >> 2] = vv[i];
    }
    __syncthreads();

    f32x4 s[4];
#pragma unroll
    for (int fc = 0; fc < 4; ++fc) {
      bf16x8 kf = *(const bf16x8*)&Klds[fc * 16 + l15][l4 * 8];
      s[fc] = __builtin_amdgcn_mfma_f32_16x16x32_bf16(qf, kf, (f32x4){0.f, 0.f, 0.f, 0.f}, 0, 0, 0);
    }
#pragma unroll
    for (int fc = 0; fc < 4; ++fc) {
      bool oob = (k0 + fc * 16 + l15) >= NQ;
#pragma unroll
      for (int j = 0; j < 4; ++j)
        s[fc][j] = oob ? -1e30f : s[fc][j] * ATT_SCALE;
    }
#pragma unroll
    for (int j = 0; j < 4; ++j) {
      float tm = fmaxf(fmaxf(s[0][j], s[1][j]), fmaxf(s[2][j], s[3][j]));
      tm = fmaxf(tm, __shfl_xor(tm, 1, 16));
      tm = fmaxf(tm, __shfl_xor(tm, 2, 16));
      tm = fmaxf(tm, __shfl_xor(tm, 4, 16));
      tm = fmaxf(tm, __shfl_xor(tm, 8, 16));
      float mn = fmaxf(m_r[j], tm);
      float sf = __expf(m_r[j] - mn);
      m_r[j] = mn;
      oacc[0][j] *= sf;
      oacc[1][j] *= sf;
      float rs = 0.f;
#pragma unroll
      for (int fc = 0; fc < 4; ++fc) {
        float pv = __expf(s[fc][j] - mn);
        s[fc][j] = pv;
        rs += pv;
      }
      rs += __shfl_xor(rs, 1, 16);
      rs += __shfl_xor(rs, 2, 16);
      rs += __shfl_xor(rs, 4, 16);
      rs += __shfl_xor(rs, 8, 16);
      l_r[j] = l_r[j] * sf + rs;
    }
#pragma unroll
    for (int fc = 0; fc < 4; ++fc)
#pragma unroll
      for (int j = 0; j < 4; ++j)
        Plds[wq * 16 + l4 * 4 + j][fc * 16 + l15] = f2b(s[fc][j]);
    __syncthreads();
#pragma unroll
    for (int ks = 0; ks < 2; ++ks) {
      bf16x8 pf = *(const bf16x8*)&Plds[wq * 16 + l15][ks * 32 + l4 * 8];
#pragma unroll
      for (int oc = 0; oc < 2; ++oc) {
        bf16x8 vf = *(const bf16x8*)&Vt[oc * 16 + l15][ks * 32 + l4 * 8];
        oacc[oc] = __builtin_amdgcn_mfma_f32_16x16x32_bf16(pf, vf, oacc[oc], 0, 0, 0);
      }
    }
  }
#pragma unroll
  for (int j = 0; j < 4; ++j) {
    int q = q0 + wq * 16 + l4 * 4 + j;
    if (q < NQ) {
      float inv = 1.f / l_r[j];
      o[(rowb + q) * 256 + hq + l15] = f2b(oacc[0][j] * inv);
      o[(rowb + q) * 256 + hq + 16 + l15] = f2b(oacc[1][j] * inv);
    }
  }
}

// ---------------------------------------------------------------- MSDA sample (unchanged)
__global__ __launch_bounds__(256) void msda_k(const float* __restrict__ refp,
                                              const float* __restrict__ vr,
                                              const unsigned short* __restrict__ value,
                                              const float* __restrict__ cat,
                                              unsigned short* __restrict__ outp) {
  const int HW[4][2] = {{92, 160}, {46, 80}, {23, 40}, {12, 20}};
  const int START[4] = {0, 14720, 18400, 19320};
  const int qi = blockIdx.x, b = blockIdx.y;
  const int tid = threadIdx.x;
  const int h = tid >> 5;
  const int r = tid & 31;
  const int lvl = r >> 3;
  const int li = r & 7;
  const size_t base = (size_t)(b * NQ + qi);
  const float rx = refp[base * 3 + 0];
  const float rz = refp[base * 3 + 2];

  const float* lg = cat + base * 384 + 256 + h * 16;
  float4 L0 = *(const float4*)(lg + 0);
  float4 L1 = *(const float4*)(lg + 4);
  float4 L2 = *(const float4*)(lg + 8);
  float4 L3 = *(const float4*)(lg + 12);
  float mx = fmaxf(fmaxf(fmaxf(L0.x, L0.y), fmaxf(L0.z, L0.w)),
                   fmaxf(fmaxf(fmaxf(L1.x, L1.y), fmaxf(L1.z, L1.w)),
                         fmaxf(fmaxf(fmaxf(L2.x, L2.y), fmaxf(L2.z, L2.w)),
                               fmaxf(fmaxf(L3.x, L3.y), fmaxf(L3.z, L3.w)))));
  float4 E0 = {__expf(L0.x - mx), __expf(L0.y - mx), __expf(L0.z - mx), __expf(L0.w - mx)};
  float4 E1 = {__expf(L1.x - mx), __expf(L1.y - mx), __expf(L1.z - mx), __expf(L1.w - mx)};
  float4 E2 = {__expf(L2.x - mx), __expf(L2.y - mx), __expf(L2.z - mx), __expf(L2.w - mx)};
  float4 E3 = {__expf(L3.x - mx), __expf(L3.y - mx), __expf(L3.z - mx), __expf(L3.w - mx)};
  float sum = E0.x + E0.y + E0.z + E0.w + E1.x + E1.y + E1.z + E1.w +
              E2.x + E2.y + E2.z + E2.w + E3.x + E3.y + E3.z + E3.w;
  const float inv = 1.f / sum;
  float4 Emy = lvl == 0 ? E0 : lvl == 1 ? E1 : lvl == 2 ? E2 : E3;
  float wl[4] = {Emy.x * inv, Emy.y * inv, Emy.z * inv, Emy.w * inv};

  const int H = HW[lvl][0], W = HW[lvl][1];
  const float refx = rx * vr[(b * LEVELS + lvl) * 2 + 0] * (float)W;
  const float refy = rz * vr[(b * LEVELS + lvl) * 2 + 1] * (float)H;
  const unsigned short* vbase = value + ((size_t)b * SLEN + START[lvl]) * DMODEL + h * DHEAD + li * 4;
  const float* ob = cat + base * 384 + h * 32 + lvl * 8;

  float a0 = 0.f, a1 = 0.f, a2 = 0.f, a3 = 0.f;
#pragma unroll
  for (int p = 0; p < 4; ++p) {
    const float x = refx + ob[p * 2 + 0] - 0.5f;
    const float y = refy + ob[p * 2 + 1] - 0.5f;
    const float x0f = floorf(x), y0f = floorf(y);
    const float fx = x - x0f, fy = y - y0f;
    const int x0 = (int)x0f, y0 = (int)y0f;
#pragma unroll
    for (int ci = 0; ci < 4; ++ci) {
      const int xi = x0 + (ci & 1);
      const int yi = y0 + (ci >> 1);
      if ((xi >= 0) && (xi < W) && (yi >= 0) && (yi < H)) {
        const float wxy = ((ci & 1) ? fx : 1.f - fx) * ((ci >> 1) ? fy : 1.f - fy) * wl[p];
        u16x4 v4 = *(const u16x4*)(vbase + (size_t)(yi * W + xi) * DMODEL);
        a0 = fmaf(wxy, b2f(v4[0]), a0);
        a1 = fmaf(wxy, b2f(v4[1]), a1);
        a2 = fmaf(wxy, b2f(v4[2]), a2);
        a3 = fmaf(wxy, b2f(v4[3]), a3);
      }
    }
  }
  a0 += __shfl_xor(a0, 8);  a1 += __shfl_xor(a1, 8);
  a2 += __shfl_xor(a2, 8);  a3 += __shfl_xor(a3, 8);
  a0 += __shfl_xor(a0, 16); a1 += __shfl_xor(a1, 16);
  a2 += __shfl_xor(a2, 16); a3 += __shfl_xor(a3, 16);
  if (lvl == 0) {
    u16x4 o4 = {f2b(a0), f2b(a1), f2b(a2), f2b(a3)};
    *(u16x4*)(outp + base * 256 + h * 32 + li * 4) = o4;
  }
}

// ---------------------------------------------------------------- launcher
extern "C" void kernel_launch(void* const* d_in, const int* in_sizes, int n_in,
                              void* d_out, int out_size, void* d_ws, size_t ws_size,
                              hipStream_t stream) {
  const float* tgt     = (const float*)d_in[0];
  const float* refp    = (const float*)d_in[1];
  const float* src     = (const float*)d_in[2];
  const float* vr      = (const float*)d_in[3];
  const float* qpos    = (const float*)d_in[4];
  const float* sa_in_w = (const float*)d_in[5];
  const float* sa_in_b = (const float*)d_in[6];
  const float* sa_out_w= (const float*)d_in[7];
  const float* sa_out_b= (const float*)d_in[8];
  const float* samp_w  = (const float*)d_in[9];
  const float* samp_b  = (const float*)d_in[10];
  const float* attn_w  = (const float*)d_in[11];
  const float* attn_b  = (const float*)d_in[12];
  const float* val_w   = (const float*)d_in[13];
  const float* val_b   = (const float*)d_in[14];
  const float* ca_out_w= (const float*)d_in[15];
  const float* ca_out_b= (const float*)d_in[16];
  const float* ffn1_w  = (const float*)d_in[17];
  const float* ffn1_b  = (const float*)d_in[18];
  const float* ffn2_w  = (const float*)d_in[19];
  const float* ffn2_b  = (const float*)d_in[20];
  const float* ln1_w   = (const float*)d_in[21];
  const float* ln1_b   = (const float*)d_in[22];
  const float* ln2_w   = (const float*)d_in[23];
  const float* ln2_b   = (const float*)d_in[24];
  const float* ln3_w   = (const float*)d_in[25];
  const float* ln3_b   = (const float*)d_in[26];

  const int M = BS * NQ;                 // 3600
  const int MV = BS * SLEN;              // 78240
  const size_t TOK = (size_t)M * DMODEL; // 921600

  float* ws = (float*)d_ws;
  size_t off = 0;
  auto alloc = [&](size_t n) { float* p = ws + off; off += n; return p; };
  auto allocb = [&](size_t n) { unsigned short* p = (unsigned short*)(ws + off); off += (n + 1) / 2; return p; };
  float* cur     = alloc(TOK);
  float* catout  = alloc((size_t)M * 384);
  float* b_cacat = alloc((size_t)NLAYERS * 384);
  unsigned short* cur_bf  = allocb(TOK);
  unsigned short* qbuf_bf = allocb(TOK);
  unsigned short* sao_bf  = allocb(TOK);
  unsigned short* msda_bf = allocb(TOK);
  unsigned short* qkv_bf  = allocb((size_t)M * 768);
  unsigned short* ffnh_bf = allocb((size_t)M * DFF);
  unsigned short* src_bf  = allocb((size_t)MV * DMODEL);
  unsigned short* value_bf= allocb((size_t)MV * DMODEL);
  unsigned short* w_in_bf   = allocb((size_t)NLAYERS * 768 * 256);
  unsigned short* w_saout_bf= allocb((size_t)NLAYERS * 256 * 256);
  unsigned short* w_cacat_bf= allocb((size_t)NLAYERS * 384 * 256);
  unsigned short* w_val_bf  = allocb((size_t)NLAYERS * 256 * 256);
  unsigned short* w_caout_bf= allocb((size_t)NLAYERS * 256 * 256);
  unsigned short* w_ffn1_bf = allocb((size_t)NLAYERS * DFF * 256);
  unsigned short* w_ffn2_bf = allocb((size_t)NLAYERS * 256 * DFF);

  const int n4 = (int)(TOK / 4);
  const dim3 blk(256);
  const dim3 gE((n4 + 255) / 256);

  copycvt_k<<<gE, blk, 0, stream>>>(tgt, qpos, cur, cur_bf, qbuf_bf, n4);
  f2ball_k<<<dim3(2048), blk, 0, stream>>>(src, sa_in_w, sa_out_w, val_w, ca_out_w,
                                           ffn1_w, ffn2_w,
                                           src_bf, w_in_bf, w_saout_bf, w_val_bf,
                                           w_caout_bf, w_ffn1_bf, w_ffn2_bf);
  catw_k<<<dim3(576), blk, 0, stream>>>(samp_w, attn_w, samp_b, attn_b, w_cacat_bf, b_cacat);

  const int BIG = 1 << 30;
  const dim3 gQKV(57, 12);   // N=768
  const dim3 gCat(57, 6);    // N=384
  const dim3 gF1(57, 16);    // N=1024
  const dim3 gLN(225);       // fused gemm+LN, 16-row tiles

  for (int l = 0; l < NLAYERS; ++l) {
    gemm_bf_k<<<gQKV, blk, 0, stream>>>(qbuf_bf, cur_bf, 512,
                                        w_in_bf + (size_t)l * 768 * 256,
                                        sa_in_b + l * 768,
                                        nullptr, qkv_bf, 768, M, 768, 256, 0);

    fattn_mfma_k<<<dim3((NQ + 63) / 64, HEADS, BS), blk, 0, stream>>>(qkv_bf, sao_bf);

    gemm_lnres_k<<<gLN, blk, 0, stream>>>(sao_bf, w_saout_bf + (size_t)l * 256 * 256,
                                          sa_out_b + l * 256, cur,
                                          ln1_w + l * 256, ln1_b + l * 256, qpos,
                                          cur, nullptr, qbuf_bf, M, 256);

    gemm_vmfma_k<<<dim3((MV + 127) / 128, 2), blk, 0, stream>>>(
        src_bf, w_val_bf + (size_t)l * 256 * 256, val_b + l * 256, value_bf, MV);
    gemm_bf_k<<<gCat, blk, 0, stream>>>(qbuf_bf, qbuf_bf, BIG,
                                        w_cacat_bf + (size_t)l * 384 * 256,
                                        b_cacat + l * 384,
                                        catout, nullptr, 384, M, 384, 256, 0);

    msda_k<<<dim3(NQ, BS), blk, 0, stream>>>(refp, vr, value_bf, catout, msda_bf);

    gemm_lnres_k<<<gLN, blk, 0, stream>>>(msda_bf, w_caout_bf + (size_t)l * 256 * 256,
                                          ca_out_b + l * 256, cur,
                                          ln2_w + l * 256, ln2_b + l * 256, nullptr,
                                          cur, cur_bf, nullptr, M, 256);

    gemm_bf_k<<<gF1, blk, 0, stream>>>(cur_bf, cur_bf, BIG,
                                       w_ffn1_bf + (size_t)l * DFF * 256,
                                       ffn1_b + l * DFF,
                                       nullptr, ffnh_bf, DFF, M, DFF, 256, 1);
    const bool last = (l == NLAYERS - 1);
    gemm_lnres_k<<<gLN, blk, 0, stream>>>(ffnh_bf, w_ffn2_bf + (size_t)l * 256 * DFF,
                                          ffn2_b + l * 256, cur,
                                          ln3_w + l * 256, ln3_b + l * 256,
                                          last ? nullptr : qpos,
                                          last ? (float*)d_out : cur,
                                          last ? nullptr : cur_bf,
                                          last ? nullptr : qbuf_bf, M, DFF);
  }
}